// Round 5
// baseline (392.794 us; speedup 1.0000x reference)
//
#include <hip/hip_runtime.h>

#define HIDDEN 128
#define NEG_SLOPE 0.2f
#define P_SORT 256          // blocks for phase-1 bucket sort

typedef unsigned short ushort_t;
typedef __attribute__((ext_vector_type(8))) short short8;
typedef __attribute__((ext_vector_type(4))) float floatx4;

static inline size_t align_up(size_t x, size_t a){ return (x + a - 1) & ~(a - 1); }

__device__ __forceinline__ ushort_t f2b(float f){
  unsigned u = __float_as_uint(f);
  unsigned r = (u + 0x7FFFu + ((u >> 16) & 1u)) >> 16;
  return (ushort_t)r;
}

__device__ __forceinline__ float b2f(ushort_t u){
  return __uint_as_float(((unsigned)u) << 16);
}

// int8 row-quantized feature FMA: 8 sbytes in a uint2, coeff a already includes row scale
__device__ __forceinline__ void fma8q(float* acc, uint2 v, float a){
  int x = (int)v.x, y = (int)v.y;
  acc[0] += a * (float)((x << 24) >> 24);
  acc[1] += a * (float)((x << 16) >> 24);
  acc[2] += a * (float)((x <<  8) >> 24);
  acc[3] += a * (float)( x        >> 24);
  acc[4] += a * (float)((y << 24) >> 24);
  acc[5] += a * (float)((y << 16) >> 24);
  acc[6] += a * (float)((y <<  8) >> 24);
  acc[7] += a * (float)( y        >> 24);
}

__device__ __forceinline__ uint2 packq8(const float* f, float qi){
  unsigned a = 0, b = 0;
  int q;
  q = (int)rintf(f[0]*qi); a |= ((unsigned)q & 255u);
  q = (int)rintf(f[1]*qi); a |= ((unsigned)q & 255u) << 8;
  q = (int)rintf(f[2]*qi); a |= ((unsigned)q & 255u) << 16;
  q = (int)rintf(f[3]*qi); a |= ((unsigned)q & 255u) << 24;
  q = (int)rintf(f[4]*qi); b |= ((unsigned)q & 255u);
  q = (int)rintf(f[5]*qi); b |= ((unsigned)q & 255u) << 8;
  q = (int)rintf(f[6]*qi); b |= ((unsigned)q & 255u) << 16;
  q = (int)rintf(f[7]*qi); b |= ((unsigned)q & 255u) << 24;
  uint2 r; r.x = a; r.y = b; return r;
}

__device__ __forceinline__ uint4 pack8(const float* f){
  uint4 u;
  u.x = (unsigned)f2b(f[0]) | ((unsigned)f2b(f[1]) << 16);
  u.y = (unsigned)f2b(f[2]) | ((unsigned)f2b(f[3]) << 16);
  u.z = (unsigned)f2b(f[4]) | ((unsigned)f2b(f[5]) << 16);
  u.w = (unsigned)f2b(f[6]) | ((unsigned)f2b(f[7]) << 16);
  return u;
}

// ============ CSR build: two-pass bucketed counting sort ============

__global__ __launch_bounds__(256) void k_b1cnt(const int* __restrict__ dst,
                                               int* __restrict__ bcnt,
                                               int E, int epb, int nbkt){
  __shared__ unsigned c[256];
  int t = threadIdx.x;
  c[t] = 0;
  __syncthreads();
  int e0 = blockIdx.x * epb;
  int e1 = min(E, e0 + epb);
  for (int e = e0 + t; e < e1; e += 256) atomicAdd(&c[dst[e] >> 8], 1u);
  __syncthreads();
  if (t < nbkt) bcnt[t * P_SORT + blockIdx.x] = (int)c[t];
}

__global__ void k_scan1(const int* __restrict__ in, int* __restrict__ incl,
                        int* __restrict__ blockSums, int M){
  __shared__ int sd[256];
  int t = threadIdx.x;
  int i = blockIdx.x*256 + t;
  int v = (i < M) ? in[i] : 0;
  sd[t] = v; __syncthreads();
  for (int off = 1; off < 256; off <<= 1){
    int add = (t >= off) ? sd[t-off] : 0;
    __syncthreads();
    sd[t] += add;
    __syncthreads();
  }
  if (i < M) incl[i] = sd[t];
  if (t == 255) blockSums[blockIdx.x] = sd[255];
}

__global__ void k_scan2(const int* __restrict__ blockSums, int* __restrict__ blockOffs, int nb){
  __shared__ int sd[256];
  __shared__ int carry;
  int t = threadIdx.x;
  if (t == 0) carry = 0;
  __syncthreads();
  for (int base = 0; base < nb; base += 256){
    int i = base + t;
    int v = (i < nb) ? blockSums[i] : 0;
    sd[t] = v; __syncthreads();
    for (int off = 1; off < 256; off <<= 1){
      int add = (t >= off) ? sd[t-off] : 0;
      __syncthreads();
      sd[t] += add;
      __syncthreads();
    }
    if (i < nb) blockOffs[i] = carry + sd[t] - v;
    __syncthreads();
    if (t == 0) carry += sd[255];
    __syncthreads();
  }
}

// phase-1 scatter: per-(bucket,block) base rebuilt in LDS from incl/bcnt/blockOffs
__global__ __launch_bounds__(256) void k_b1place(const int* __restrict__ src,
                                                 const int* __restrict__ dst,
                                                 const float* __restrict__ w,
                                                 const int* __restrict__ incl,
                                                 const int* __restrict__ bcnt,
                                                 const int* __restrict__ blockOffs,
                                                 int2* __restrict__ tpw,
                                                 int E, int epb, int nbkt){
  __shared__ int base_[256];
  __shared__ unsigned c[256];
  int t = threadIdx.x;
  c[t] = 0;
  if (t < nbkt){
    int idx = t * P_SORT + blockIdx.x;
    base_[t] = incl[idx] - bcnt[idx] + blockOffs[t];
  }
  __syncthreads();
  int e0 = blockIdx.x * epb;
  int e1 = min(E, e0 + epb);
  for (int e = e0 + t; e < e1; e += 256){
    int d = dst[e];
    int b = d >> 8;
    unsigned r = atomicAdd(&c[b], 1u);
    int pos = base_[b] + (int)r;
    tpw[pos] = make_int2((int)((unsigned)src[e] | ((unsigned)(d & 255) << 16)),
                         __float_as_int(w[e]));
  }
}

// phase-2 fine sort: counting sort on key (row, src>>12)
__global__ __launch_bounds__(256) void k_b2(const int2* __restrict__ tpw,
                                            const int* __restrict__ blockOffs,
                                            int2* __restrict__ col_sw,
                                            int* __restrict__ rowp,
                                            float* __restrict__ dinv,
                                            int N, int E, int nbkt){
  __shared__ int cnt[4096];      // 256 rows x 16 src-slices
  __shared__ int tsum[256];
  __shared__ float wsum[256];
  int b = blockIdx.x, t = threadIdx.x;
  int e0 = blockOffs[b];
  int e1 = (b + 1 < nbkt) ? blockOffs[b + 1] : E;
  #pragma unroll
  for (int i = 0; i < 16; i++) cnt[t*16 + i] = 0;
  wsum[t] = 0.f;
  __syncthreads();
  for (int e = e0 + t; e < e1; e += 256){
    int2 pw = tpw[e];
    unsigned dl = ((unsigned)pw.x >> 16) & 255u;
    unsigned s  = ((unsigned)pw.x & 0xFFFFu) >> 12;     // src slice 0..15
    atomicAdd(&cnt[(dl << 4) | s], 1);
  }
  __syncthreads();
  int loc[16]; int run = 0;
  #pragma unroll
  for (int i = 0; i < 16; i++){ loc[i] = run; run += cnt[t*16 + i]; }
  tsum[t] = run;
  __syncthreads();
  for (int off = 1; off < 256; off <<= 1){
    int add = (t >= off) ? tsum[t-off] : 0;
    __syncthreads();
    tsum[t] += add;
    __syncthreads();
  }
  int base = tsum[t] - run;                              // exclusive over rows
  #pragma unroll
  for (int i = 0; i < 16; i++) cnt[t*16 + i] = base + loc[i];
  int node = b*256 + t;
  if (node < N) rowp[node] = e0 + base;
  if (b == 0 && t == 0) rowp[N] = E;
  __syncthreads();
  for (int e = e0 + t; e < e1; e += 256){
    int2 pw = tpw[e];
    unsigned dl = ((unsigned)pw.x >> 16) & 255u;
    unsigned srcv = (unsigned)pw.x & 0xFFFFu;
    unsigned s = srcv >> 12;
    int pos = e0 + atomicAdd(&cnt[(dl << 4) | s], 1);    // old value == slot
    col_sw[pos] = make_int2((int)srcv, pw.y);
    atomicAdd(&wsum[dl], __int_as_float(pw.y));
  }
  __syncthreads();
  if (node < N) dinv[node] = rsqrtf(wsum[t] + 1.0f);     // +1 = self-loop weight
}

// ---------------- weight cast (4 mats fp32 -> transposed bf16) ----------------

__global__ void k_cast_w(const float* __restrict__ Wg, const float* __restrict__ Wc,
                         ushort_t* __restrict__ Wt){
  int i = blockIdx.x*256 + threadIdx.x;       // 4*16384
  int mat = i >> 14, idx = i & 16383;
  int k = idx >> 7, n = idx & 127;
  float v = (mat == 0) ? Wg[idx] : Wc[(mat-1)*16384 + idx];
  Wt[mat*16384 + n*128 + k] = f2b(v);
}

// ------- MFMA GEMM (GAT layer): xp = x @ W_gat; outputs int8-quantized xp rows
// (zq + sc_z) and fused a_src/a_dst row dots (attr/sdst). No bf16 xp needed. -------
__global__ __launch_bounds__(128) void k_gemm1(const float* __restrict__ Ain,
                                               const ushort_t* __restrict__ Wt,
                                               unsigned* __restrict__ zq,   // N*32B (uint)
                                               float* __restrict__ sc_z,
                                               const float* __restrict__ a_src,
                                               const float* __restrict__ a_dst,
                                               const float* __restrict__ dinv,
                                               float2* __restrict__ attr,
                                               float* __restrict__ sdst, int M){
  __shared__ uint4 zq8v[64][8];                 // 64 rows x 128B int8 staging
  char (*zq8)[128] = (char(*)[128])zq8v;
  int wave = threadIdx.x >> 6, l = threadIdx.x & 63;
  int q = l >> 4, lm = l & 15;
  int rowBase = blockIdx.x*64 + wave*32;
  floatx4 acc[2][8];
  #pragma unroll
  for (int mt = 0; mt < 2; mt++)
    #pragma unroll
    for (int nt = 0; nt < 8; nt++) acc[mt][nt] = (floatx4){0.f,0.f,0.f,0.f};

  #pragma unroll
  for (int kc = 0; kc < 4; kc++){
    int k0 = kc*32 + q*8;
    short8 a[2];
    #pragma unroll
    for (int mt = 0; mt < 2; mt++){
      long r = rowBase + mt*16 + lm;
      if (r < M){
        const float* ap = Ain + r*128 + k0;
        float4 u = *(const float4*)ap;
        float4 v = *(const float4*)(ap + 4);
        short8 tv;
        tv[0]=(short)f2b(u.x); tv[1]=(short)f2b(u.y); tv[2]=(short)f2b(u.z); tv[3]=(short)f2b(u.w);
        tv[4]=(short)f2b(v.x); tv[5]=(short)f2b(v.y); tv[6]=(short)f2b(v.z); tv[7]=(short)f2b(v.w);
        a[mt] = tv;
      } else a[mt] = (short8){0,0,0,0,0,0,0,0};
    }
    #pragma unroll
    for (int nt = 0; nt < 8; nt++){
      short8 b = *(const short8*)(Wt + (nt*16 + lm)*128 + k0);
      acc[0][nt] = __builtin_amdgcn_mfma_f32_16x16x32_bf16(a[0], b, acc[0][nt], 0, 0, 0);
      acc[1][nt] = __builtin_amdgcn_mfma_f32_16x16x32_bf16(a[1], b, acc[1][nt], 0, 0, 0);
    }
  }
  // ---- int8 row quantization (C layout: row = rowBase+mt*16+q*4+r, col = nt*16+lm) ----
  #pragma unroll
  for (int mt = 0; mt < 2; mt++){
    #pragma unroll
    for (int r = 0; r < 4; r++){
      float rm = 0.f;
      #pragma unroll
      for (int nt = 0; nt < 8; nt++) rm = fmaxf(rm, fabsf(acc[mt][nt][r]));
      #pragma unroll
      for (int off = 1; off <= 8; off <<= 1) rm = fmaxf(rm, __shfl_xor(rm, off, 64));
      float qi = (rm > 0.f) ? 127.f/rm : 0.f;
      int lrow = wave*32 + mt*16 + q*4 + r;
      #pragma unroll
      for (int nt = 0; nt < 8; nt++)
        zq8[lrow][nt*16 + lm] = (char)(int)rintf(acc[mt][nt][r]*qi);
      long row = rowBase + mt*16 + q*4 + r;
      if (lm == 0 && row < M) sc_z[row] = rm * (1.f/127.f);
    }
  }
  // ---- fused attention row dots ----
  float as8[8], ad8[8];
  #pragma unroll
  for (int nt = 0; nt < 8; nt++){ as8[nt] = a_src[nt*16 + lm]; ad8[nt] = a_dst[nt*16 + lm]; }
  #pragma unroll
  for (int mt = 0; mt < 2; mt++){
    #pragma unroll
    for (int r = 0; r < 4; r++){
      float ps = 0.f, pd = 0.f;
      #pragma unroll
      for (int nt = 0; nt < 8; nt++){
        ps += acc[mt][nt][r] * as8[nt];
        pd += acc[mt][nt][r] * ad8[nt];
      }
      #pragma unroll
      for (int off = 1; off <= 8; off <<= 1){
        ps += __shfl_xor(ps, off, 64);
        pd += __shfl_xor(pd, off, 64);
      }
      long row = rowBase + mt*16 + q*4 + r;
      if (lm == 0 && row < M){
        attr[row] = make_float2(ps, dinv[row]);
        sdst[row] = pd;
      }
    }
  }
  __syncthreads();
  // ---- coalesced dump of int8 rows ----
  {
    int t = threadIdx.x;
    int lrow = t >> 1, half = t & 1;
    long row = (long)blockIdx.x*64 + lrow;
    if (row < M){
      uint4* dq = (uint4*)zq + row*8 + half*4;
      #pragma unroll
      for (int k = 0; k < 4; k++) dq[k] = zq8v[lrow][half*4 + k];
    }
  }
}

// ======= GAT aggregation: wave per node, 16 lanes/edge; int8 gather =======
// postprocess folds sc_z[src] into col_ea; epilogue writes bf16 h0 (for JK),
// int8 g0 + scd0 (= sc0 * dinv) for the next layer's gather.
__global__ __launch_bounds__(256) void k_agg0(const unsigned* __restrict__ zq,
                                              const float* __restrict__ sc_z,
                                              const int* __restrict__ rowp,
                                              const int2* __restrict__ col_sw,
                                              int2* __restrict__ col_ea,
                                              const float2* __restrict__ attr,
                                              const float* __restrict__ sdst_,
                                              const float* __restrict__ bias,
                                              ushort_t* __restrict__ out,
                                              unsigned* __restrict__ g0,
                                              float* __restrict__ scd0, int N){
  int n = blockIdx.x*4 + (threadIdx.x >> 6);
  if (n >= N) return;
  int l = threadIdx.x & 63;
  int rs = rowp[n], re = rowp[n+1];
  float2 an = attr[n];
  float sdd = sdst_[n];
  float es = an.x + sdd;
  es = (es >= 0.f) ? es : NEG_SLOPE*es;
  float pself = __expf(es);
  float ps = 0.f;
  for (int j = rs + l; j < re; j += 64){
    int2 sw = col_sw[j];
    float2 a = attr[sw.x];
    float ee = a.x + sdd;
    ee = (ee >= 0.f) ? ee : NEG_SLOPE*ee;
    float pe = __expf(ee);
    ps += pe;
    col_ea[j] = make_int2(sw.x, __float_as_int(pe * sc_z[sw.x]));
  }
  #pragma unroll
  for (int off = 32; off >= 1; off >>= 1) ps += __shfl_xor(ps, off, 64);
  float inv = 1.f / (ps + pself);

  int sub = l >> 4, q = l & 15;
  const uint2* f8 = (const uint2*)zq;
  float acc[8] = {0.f,0.f,0.f,0.f,0.f,0.f,0.f,0.f};
  for (int base = rs; base < re; base += 24){
    int2 p[6]; float a[6];
    #pragma unroll
    for (int j = 0; j < 6; j++){
      int e = base + sub + 4*j;
      int cc = min(e, re-1);
      p[j] = col_ea[cc];
      a[j] = (e < re) ? __int_as_float(p[j].y) : 0.f;
    }
    uint2 v[6];
    #pragma unroll
    for (int j = 0; j < 6; j++) v[j] = f8[(size_t)p[j].x*16 + q];
    #pragma unroll
    for (int j = 0; j < 6; j++) fma8q(acc, v[j], a[j]);
  }
  #pragma unroll
  for (int j = 0; j < 8; j++){
    acc[j] += __shfl_xor(acc[j], 16, 64);
    acc[j] += __shfl_xor(acc[j], 32, 64);
  }
  if (sub == 0){
    #pragma unroll
    for (int j = 0; j < 8; j++) acc[j] *= inv;
    fma8q(acc, f8[(size_t)n*16 + q], pself * inv * sc_z[n]);
    float4 b0 = ((const float4*)bias)[q*2];
    float4 b1 = ((const float4*)bias)[q*2 + 1];
    acc[0]+=b0.x; acc[1]+=b0.y; acc[2]+=b0.z; acc[3]+=b0.w;
    acc[4]+=b1.x; acc[5]+=b1.y; acc[6]+=b1.z; acc[7]+=b1.w;
    ((uint4*)out)[(size_t)n*16 + q] = pack8(acc);        // bf16 h0 for JK
    // int8 quantize h0 row (16 lanes hold the row: lane q = cols q*8..q*8+7)
    float rm = 0.f;
    #pragma unroll
    for (int j = 0; j < 8; j++) rm = fmaxf(rm, fabsf(acc[j]));
    #pragma unroll
    for (int off = 1; off <= 8; off <<= 1) rm = fmaxf(rm, __shfl_xor(rm, off, 64));
    float qi = (rm > 0.f) ? 127.f/rm : 0.f;
    ((uint2*)g0)[(size_t)n*16 + q] = packq8(acc, qi);
    if (l == 0) scd0[n] = rm * (1.f/127.f) * an.y;       // sc0 * dinv[n]
  }
}

// ======= fused GCN layer, int8 gather: h' = relu((A h) W + b) =======
// coeff per edge = w * scd_prev[src]; acc scaled by dinv[n] once; self = scd_prev[n].
// Block = 16 nodes. Phase 1: gather-agg -> bf16 rows in LDS. Phase 2: MFMA x W.
// MODE 1: write bf16 h' + int8 g' + scd'. MODE 2: last layer + JK max -> fp32 out.
template<int MODE>
__global__ __launch_bounds__(256) void k_fagg(const unsigned* __restrict__ gin,
                                              const float* __restrict__ scd_prev,
                                              const int* __restrict__ rowp,
                                              const int2* __restrict__ col_sw,
                                              const float* __restrict__ dinv,
                                              const ushort_t* __restrict__ Wl,
                                              const float* __restrict__ bias,
                                              ushort_t* __restrict__ out,
                                              unsigned* __restrict__ gout,
                                              float* __restrict__ scd_out,
                                              const ushort_t* __restrict__ j0,
                                              const ushort_t* __restrict__ j1,
                                              const ushort_t* __restrict__ j2,
                                              float* __restrict__ yout, int N){
  __shared__ ushort_t At[16][136];             // +8 pad: break LDS bank aliasing
  __shared__ uint4 q8v[16][8];                 // int8 output staging (16 x 128B)
  __shared__ unsigned rmaxs[16];
  char (*q8s)[128] = (char(*)[128])q8v;
  int wave = threadIdx.x >> 6, l = threadIdx.x & 63;
  int sub = l >> 4, q = l & 15;
  const uint2* f8 = (const uint2*)gin;
  int tile = blockIdx.x * 16;

  // ---- phase 1: aggregate 4 nodes per wave into LDS (bf16 rows) ----
  for (int i = 0; i < 4; i++){
    int row = wave*4 + i;
    int n = tile + row;
    int rs = 0, re = 0; float dn = 0.f, sprev = 0.f;
    if (n < N){ rs = rowp[n]; re = rowp[n+1]; dn = dinv[n]; sprev = scd_prev[n]; }
    float acc[8] = {0.f,0.f,0.f,0.f,0.f,0.f,0.f,0.f};
    for (int base = rs; base < re; base += 24){
      int2 p[6]; float a[6];
      #pragma unroll
      for (int j = 0; j < 6; j++){
        int e = base + sub + 4*j;
        int cc = min(e, re-1);
        p[j] = col_sw[cc];
        a[j] = (e < re) ? __int_as_float(p[j].y) * scd_prev[p[j].x] : 0.f;
      }
      uint2 v[6];
      #pragma unroll
      for (int j = 0; j < 6; j++) v[j] = f8[(size_t)p[j].x*16 + q];
      #pragma unroll
      for (int j = 0; j < 6; j++) fma8q(acc, v[j], a[j]);
    }
    #pragma unroll
    for (int j = 0; j < 8; j++){
      acc[j] += __shfl_xor(acc[j], 16, 64);
      acc[j] += __shfl_xor(acc[j], 32, 64);
    }
    if (sub == 0){
      if (n < N) fma8q(acc, f8[(size_t)n*16 + q], sprev);   // self-loop term
      #pragma unroll
      for (int j = 0; j < 8; j++) acc[j] *= dn;             // hoisted dinv[n]
      *(uint4*)&At[row][q*8] = pack8(acc);                  // zeros for n >= N
    }
  }
  if (threadIdx.x < 16) rmaxs[threadIdx.x] = 0u;
  __syncthreads();

  // ---- phase 2: [16x128] @ [128x128] ; wave covers 32 output cols ----
  floatx4 co[2];
  co[0] = (floatx4){0.f,0.f,0.f,0.f};
  co[1] = (floatx4){0.f,0.f,0.f,0.f};
  #pragma unroll
  for (int kc = 0; kc < 4; kc++){
    int k0 = kc*32 + sub*8;
    short8 a = *(const short8*)&At[q][k0];
    #pragma unroll
    for (int ntl = 0; ntl < 2; ntl++){
      int nt = wave*2 + ntl;
      short8 b = *(const short8*)(Wl + (size_t)(nt*16 + q)*128 + k0);
      co[ntl] = __builtin_amdgcn_mfma_f32_16x16x32_bf16(a, b, co[ntl], 0, 0, 0);
    }
  }
  // C layout: col = lane&15 (=q), row = sub*4 + r
  float vv[4][2];
  #pragma unroll
  for (int r = 0; r < 4; r++){
    int row = sub*4 + r;
    int node = tile + row;
    float lmax = 0.f;
    #pragma unroll
    for (int ntl = 0; ntl < 2; ntl++){
      int colg = wave*32 + ntl*16 + q;
      float v = co[ntl][r] + bias[colg];
      v = fmaxf(v, 0.f);                       // all GCN layers ReLU'd
      vv[r][ntl] = v;
      lmax = fmaxf(lmax, v);
      if (node < N){
        size_t idx = (size_t)node*128 + colg;
        if (MODE == 1){
          out[idx] = f2b(v);                   // bf16 h' for JK
        } else {
          float m = fmaxf(fmaxf(b2f(j0[idx]), b2f(j1[idx])),
                          fmaxf(b2f(j2[idx]), v));
          yout[idx] = m;
        }
      }
    }
    if (MODE == 1) atomicMax(&rmaxs[row], __float_as_uint(lmax));  // v>=0: bits ordered
  }
  if (MODE == 1){
    __syncthreads();
    #pragma unroll
    for (int r = 0; r < 4; r++){
      int row = sub*4 + r;
      float rm = __uint_as_float(rmaxs[row]);
      float qi = (rm > 0.f) ? 127.f/rm : 0.f;
      #pragma unroll
      for (int ntl = 0; ntl < 2; ntl++){
        int colg = wave*32 + ntl*16 + q;
        q8s[row][colg] = (char)(int)rintf(vv[r][ntl]*qi);
      }
    }
    if (threadIdx.x < 16){
      int node = tile + threadIdx.x;
      if (node < N){
        float rm = __uint_as_float(rmaxs[threadIdx.x]);
        scd_out[node] = rm * (1.f/127.f) * dinv[node];
      }
    }
    __syncthreads();
    if (threadIdx.x < 128){
      int row = threadIdx.x >> 3, c = threadIdx.x & 7;
      int node = tile + row;
      if (node < N) ((uint4*)gout)[(size_t)node*8 + c] = q8v[row][c];
    }
  }
}

extern "C" void kernel_launch(void* const* d_in, const int* in_sizes, int n_in,
                              void* d_out, int out_size, void* d_ws, size_t ws_size,
                              hipStream_t stream){
  const float* x      = (const float*)d_in[0];
  const int*   eidx   = (const int*)d_in[1];
  const float* emask  = (const float*)d_in[2];
  const float* W_gat  = (const float*)d_in[3];
  const float* a_src  = (const float*)d_in[4];
  const float* a_dst  = (const float*)d_in[5];
  const float* b_gat  = (const float*)d_in[6];
  const float* W_gcn  = (const float*)d_in[7];
  const float* b_gcn  = (const float*)d_in[8];
  int N = in_sizes[0] / HIDDEN;
  int E = in_sizes[1] / 2;
  const int* src = eidx;
  const int* dst = eidx + E;

  char* p = (char*)d_ws;
  auto carve = [&](size_t bytes)->char*{ char* q = p; p += align_up(bytes, 512); return q; };
  ushort_t* h0   = (ushort_t*)carve((size_t)N*HIDDEN*2);
  ushort_t* h1   = (ushort_t*)carve((size_t)N*HIDDEN*2);
  ushort_t* h2   = (ushort_t*)carve((size_t)N*HIDDEN*2);
  ushort_t* Wt   = (ushort_t*)carve((size_t)4*HIDDEN*HIDDEN*2);
  unsigned* zq   = (unsigned*)carve((size_t)N*HIDDEN);      // int8 matrices (128B rows)
  unsigned* g0q  = (unsigned*)carve((size_t)N*HIDDEN);
  unsigned* g1q  = (unsigned*)carve((size_t)N*HIDDEN);
  unsigned* g2q  = (unsigned*)carve((size_t)N*HIDDEN);
  float* sc_z    = (float*)carve((size_t)N*4);
  float* scd0    = (float*)carve((size_t)N*4);
  float* scd1    = (float*)carve((size_t)N*4);
  float* scd2    = (float*)carve((size_t)N*4);
  float2* attr   = (float2*)carve((size_t)N*8);
  float* sdst    = (float*)carve((size_t)N*4);
  float* dinv    = (float*)carve((size_t)N*4);
  int*   rowp    = (int*)  carve((size_t)(N+1)*4);
  int2*  col_sw  = (int2*) carve((size_t)E*8);
  int2*  col_ea  = (int2*) carve((size_t)E*8);
  int2*  tpw     = (int2*) carve((size_t)E*8);
  int nbkt = (N + 255) >> 8;                       // 196
  int M    = nbkt * P_SORT;                        // 50176
  int*   bcnt  = (int*)carve((size_t)M*4);
  int*   incl  = (int*)carve((size_t)M*4);
  int nbs = (M + 255) / 256;                       // == nbkt
  int*   blockSums = (int*)carve((size_t)nbs*4);
  int*   blockOffs = (int*)carve((size_t)nbs*4);
  (void)ws_size; (void)n_in; (void)out_size;

  int epb = (E + P_SORT - 1) / P_SORT;
  int gb  = (N + 63) / 64;
  int nwb = (N + 3) / 4;
  int nfb = (N + 15) / 16;

  // CSR build (atomic-free, full-chip)
  k_b1cnt  <<<P_SORT, 256, 0, stream>>>(dst, bcnt, E, epb, nbkt);
  k_scan1  <<<nbs, 256, 0, stream>>>(bcnt, incl, blockSums, M);
  k_scan2  <<<1,   256, 0, stream>>>(blockSums, blockOffs, nbs);
  k_b1place<<<P_SORT, 256, 0, stream>>>(src, dst, emask, incl, bcnt, blockOffs,
                                        tpw, E, epb, nbkt);
  k_b2     <<<nbkt, 256, 0, stream>>>(tpw, blockOffs, col_sw, rowp, dinv, N, E, nbkt);

  // weights
  k_cast_w<<<(4*HIDDEN*HIDDEN)/256, 256, 0, stream>>>(W_gat, W_gcn, Wt);

  // xp = x @ W_gat -> int8 rows + scales + fused attention dots
  k_gemm1<<<gb, 128, 0, stream>>>(x, Wt, zq, sc_z, a_src, a_dst, dinv, attr, sdst, N);

  // GAT aggregation (int8 gather), produces h0 bf16 + g0 int8 + scd0
  k_agg0<<<nwb, 256, 0, stream>>>(zq, sc_z, rowp, col_sw, col_ea, attr, sdst,
                                  b_gat, h0, g0q, scd0, N);

  // fused GCN layers: h' = relu((A h) W + b)   [A(hW) == (Ah)W]
  k_fagg<1><<<nfb, 256, 0, stream>>>(g0q, scd0, rowp, col_sw, dinv,
                                     Wt + (size_t)1*16384, b_gcn + 0,
                                     h1, g1q, scd1,
                                     nullptr, nullptr, nullptr, nullptr, N);
  k_fagg<1><<<nfb, 256, 0, stream>>>(g1q, scd1, rowp, col_sw, dinv,
                                     Wt + (size_t)2*16384, b_gcn + 128,
                                     h2, g2q, scd2,
                                     nullptr, nullptr, nullptr, nullptr, N);
  // last layer + fused JK max over {h0, h1, h2, h3} -> fp32 d_out
  k_fagg<2><<<nfb, 256, 0, stream>>>(g2q, scd2, rowp, col_sw, dinv,
                                     Wt + (size_t)3*16384, b_gcn + 256,
                                     nullptr, nullptr, nullptr,
                                     h0, h1, h2, (float*)d_out, N);
}

// Round 6
// 346.560 us; speedup vs baseline: 1.1334x; 1.1334x over previous
//
#include <hip/hip_runtime.h>

#define HIDDEN 128
#define NEG_SLOPE 0.2f
#define P_SORT 256          // blocks for phase-1 bucket sort

typedef unsigned short ushort_t;
typedef __attribute__((ext_vector_type(8))) short short8;
typedef __attribute__((ext_vector_type(4))) float floatx4;

static inline size_t align_up(size_t x, size_t a){ return (x + a - 1) & ~(a - 1); }

__device__ __forceinline__ ushort_t f2b(float f){
  unsigned u = __float_as_uint(f);
  unsigned r = (u + 0x7FFFu + ((u >> 16) & 1u)) >> 16;
  return (ushort_t)r;
}

__device__ __forceinline__ float b2f(ushort_t u){
  return __uint_as_float(((unsigned)u) << 16);
}

// int8 row-quantized feature FMA: 8 sbytes in a uint2, coeff a already includes row scale
__device__ __forceinline__ void fma8q(float* acc, uint2 v, float a){
  int x = (int)v.x, y = (int)v.y;
  acc[0] += a * (float)((x << 24) >> 24);
  acc[1] += a * (float)((x << 16) >> 24);
  acc[2] += a * (float)((x <<  8) >> 24);
  acc[3] += a * (float)( x        >> 24);
  acc[4] += a * (float)((y << 24) >> 24);
  acc[5] += a * (float)((y << 16) >> 24);
  acc[6] += a * (float)((y <<  8) >> 24);
  acc[7] += a * (float)( y        >> 24);
}

__device__ __forceinline__ uint2 packq8(const float* f, float qi){
  unsigned a = 0, b = 0;
  int q;
  q = (int)rintf(f[0]*qi); a |= ((unsigned)q & 255u);
  q = (int)rintf(f[1]*qi); a |= ((unsigned)q & 255u) << 8;
  q = (int)rintf(f[2]*qi); a |= ((unsigned)q & 255u) << 16;
  q = (int)rintf(f[3]*qi); a |= ((unsigned)q & 255u) << 24;
  q = (int)rintf(f[4]*qi); b |= ((unsigned)q & 255u);
  q = (int)rintf(f[5]*qi); b |= ((unsigned)q & 255u) << 8;
  q = (int)rintf(f[6]*qi); b |= ((unsigned)q & 255u) << 16;
  q = (int)rintf(f[7]*qi); b |= ((unsigned)q & 255u) << 24;
  uint2 r; r.x = a; r.y = b; return r;
}

__device__ __forceinline__ uint4 pack8(const float* f){
  uint4 u;
  u.x = (unsigned)f2b(f[0]) | ((unsigned)f2b(f[1]) << 16);
  u.y = (unsigned)f2b(f[2]) | ((unsigned)f2b(f[3]) << 16);
  u.z = (unsigned)f2b(f[4]) | ((unsigned)f2b(f[5]) << 16);
  u.w = (unsigned)f2b(f[6]) | ((unsigned)f2b(f[7]) << 16);
  return u;
}

// ============ CSR build: two-pass bucketed counting sort ============
// merged: blocks [0, P_SORT) do the bucket count; blocks [P_SORT, P_SORT+256)
// do the independent weight cast (4 mats fp32 -> transposed bf16).

__global__ __launch_bounds__(256) void k_b1cnt_cast(const int* __restrict__ dst,
                                                    int* __restrict__ bcnt,
                                                    const float* __restrict__ Wg,
                                                    const float* __restrict__ Wc,
                                                    ushort_t* __restrict__ Wt,
                                                    int E, int epb, int nbkt){
  int t = threadIdx.x;
  if (blockIdx.x >= P_SORT){
    int i = (blockIdx.x - P_SORT)*256 + t;     // 4*16384 elements
    int mat = i >> 14, idx = i & 16383;
    int k = idx >> 7, n = idx & 127;
    float v = (mat == 0) ? Wg[idx] : Wc[(mat-1)*16384 + idx];
    Wt[mat*16384 + n*128 + k] = f2b(v);
    return;
  }
  __shared__ unsigned c[256];
  c[t] = 0;
  __syncthreads();
  int e0 = blockIdx.x * epb;
  int e1 = min(E, e0 + epb);
  for (int e = e0 + t; e < e1; e += 256) atomicAdd(&c[dst[e] >> 8], 1u);
  __syncthreads();
  if (t < nbkt) bcnt[t * P_SORT + blockIdx.x] = (int)c[t];
}

__global__ void k_scan1(const int* __restrict__ in, int* __restrict__ incl,
                        int* __restrict__ blockSums, int M){
  __shared__ int sd[256];
  int t = threadIdx.x;
  int i = blockIdx.x*256 + t;
  int v = (i < M) ? in[i] : 0;
  sd[t] = v; __syncthreads();
  for (int off = 1; off < 256; off <<= 1){
    int add = (t >= off) ? sd[t-off] : 0;
    __syncthreads();
    sd[t] += add;
    __syncthreads();
  }
  if (i < M) incl[i] = sd[t];
  if (t == 255) blockSums[blockIdx.x] = sd[255];
}

__global__ void k_scan2(const int* __restrict__ blockSums, int* __restrict__ blockOffs, int nb){
  __shared__ int sd[256];
  __shared__ int carry;
  int t = threadIdx.x;
  if (t == 0) carry = 0;
  __syncthreads();
  for (int base = 0; base < nb; base += 256){
    int i = base + t;
    int v = (i < nb) ? blockSums[i] : 0;
    sd[t] = v; __syncthreads();
    for (int off = 1; off < 256; off <<= 1){
      int add = (t >= off) ? sd[t-off] : 0;
      __syncthreads();
      sd[t] += add;
      __syncthreads();
    }
    if (i < nb) blockOffs[i] = carry + sd[t] - v;
    __syncthreads();
    if (t == 0) carry += sd[255];
    __syncthreads();
  }
}

// phase-1 scatter: per-(bucket,block) base rebuilt in LDS from incl/bcnt/blockOffs
__global__ __launch_bounds__(256) void k_b1place(const int* __restrict__ src,
                                                 const int* __restrict__ dst,
                                                 const float* __restrict__ w,
                                                 const int* __restrict__ incl,
                                                 const int* __restrict__ bcnt,
                                                 const int* __restrict__ blockOffs,
                                                 int2* __restrict__ tpw,
                                                 int E, int epb, int nbkt){
  __shared__ int base_[256];
  __shared__ unsigned c[256];
  int t = threadIdx.x;
  c[t] = 0;
  if (t < nbkt){
    int idx = t * P_SORT + blockIdx.x;
    base_[t] = incl[idx] - bcnt[idx] + blockOffs[t];
  }
  __syncthreads();
  int e0 = blockIdx.x * epb;
  int e1 = min(E, e0 + epb);
  for (int e = e0 + t; e < e1; e += 256){
    int d = dst[e];
    int b = d >> 8;
    unsigned r = atomicAdd(&c[b], 1u);
    int pos = base_[b] + (int)r;
    tpw[pos] = make_int2((int)((unsigned)src[e] | ((unsigned)(d & 255) << 16)),
                         __float_as_int(w[e]));
  }
}

// phase-2 fine sort: counting sort on key (row, src>>12)
__global__ __launch_bounds__(256) void k_b2(const int2* __restrict__ tpw,
                                            const int* __restrict__ blockOffs,
                                            int2* __restrict__ col_sw,
                                            int* __restrict__ rowp,
                                            float* __restrict__ dinv,
                                            int N, int E, int nbkt){
  __shared__ int cnt[4096];      // 256 rows x 16 src-slices
  __shared__ int tsum[256];
  __shared__ float wsum[256];
  int b = blockIdx.x, t = threadIdx.x;
  int e0 = blockOffs[b];
  int e1 = (b + 1 < nbkt) ? blockOffs[b + 1] : E;
  #pragma unroll
  for (int i = 0; i < 16; i++) cnt[t*16 + i] = 0;
  wsum[t] = 0.f;
  __syncthreads();
  for (int e = e0 + t; e < e1; e += 256){
    int2 pw = tpw[e];
    unsigned dl = ((unsigned)pw.x >> 16) & 255u;
    unsigned s  = ((unsigned)pw.x & 0xFFFFu) >> 12;     // src slice 0..15
    atomicAdd(&cnt[(dl << 4) | s], 1);
  }
  __syncthreads();
  int loc[16]; int run = 0;
  #pragma unroll
  for (int i = 0; i < 16; i++){ loc[i] = run; run += cnt[t*16 + i]; }
  tsum[t] = run;
  __syncthreads();
  for (int off = 1; off < 256; off <<= 1){
    int add = (t >= off) ? tsum[t-off] : 0;
    __syncthreads();
    tsum[t] += add;
    __syncthreads();
  }
  int base = tsum[t] - run;                              // exclusive over rows
  #pragma unroll
  for (int i = 0; i < 16; i++) cnt[t*16 + i] = base + loc[i];
  int node = b*256 + t;
  if (node < N) rowp[node] = e0 + base;
  if (b == 0 && t == 0) rowp[N] = E;
  __syncthreads();
  for (int e = e0 + t; e < e1; e += 256){
    int2 pw = tpw[e];
    unsigned dl = ((unsigned)pw.x >> 16) & 255u;
    unsigned srcv = (unsigned)pw.x & 0xFFFFu;
    unsigned s = srcv >> 12;
    int pos = e0 + atomicAdd(&cnt[(dl << 4) | s], 1);    // old value == slot
    col_sw[pos] = make_int2((int)srcv, pw.y);
    atomicAdd(&wsum[dl], __int_as_float(pw.y));
  }
  __syncthreads();
  if (node < N) dinv[node] = rsqrtf(wsum[t] + 1.0f);     // +1 = self-loop weight
}

// ------- MFMA GEMM (GAT layer): xp = x @ W_gat; outputs int8-quantized xp rows
// (zq + sc_z) and fused a_src/a_dst row dots (attr/sdst). -------
__global__ __launch_bounds__(128) void k_gemm1(const float* __restrict__ Ain,
                                               const ushort_t* __restrict__ Wt,
                                               unsigned* __restrict__ zq,   // N*32B (uint)
                                               float* __restrict__ sc_z,
                                               const float* __restrict__ a_src,
                                               const float* __restrict__ a_dst,
                                               const float* __restrict__ dinv,
                                               float2* __restrict__ attr,
                                               float* __restrict__ sdst, int M){
  __shared__ uint4 zq8v[64][8];                 // 64 rows x 128B int8 staging
  char (*zq8)[128] = (char(*)[128])zq8v;
  int wave = threadIdx.x >> 6, l = threadIdx.x & 63;
  int q = l >> 4, lm = l & 15;
  int rowBase = blockIdx.x*64 + wave*32;
  floatx4 acc[2][8];
  #pragma unroll
  for (int mt = 0; mt < 2; mt++)
    #pragma unroll
    for (int nt = 0; nt < 8; nt++) acc[mt][nt] = (floatx4){0.f,0.f,0.f,0.f};

  #pragma unroll
  for (int kc = 0; kc < 4; kc++){
    int k0 = kc*32 + q*8;
    short8 a[2];
    #pragma unroll
    for (int mt = 0; mt < 2; mt++){
      long r = rowBase + mt*16 + lm;
      if (r < M){
        const float* ap = Ain + r*128 + k0;
        float4 u = *(const float4*)ap;
        float4 v = *(const float4*)(ap + 4);
        short8 tv;
        tv[0]=(short)f2b(u.x); tv[1]=(short)f2b(u.y); tv[2]=(short)f2b(u.z); tv[3]=(short)f2b(u.w);
        tv[4]=(short)f2b(v.x); tv[5]=(short)f2b(v.y); tv[6]=(short)f2b(v.z); tv[7]=(short)f2b(v.w);
        a[mt] = tv;
      } else a[mt] = (short8){0,0,0,0,0,0,0,0};
    }
    #pragma unroll
    for (int nt = 0; nt < 8; nt++){
      short8 b = *(const short8*)(Wt + (nt*16 + lm)*128 + k0);
      acc[0][nt] = __builtin_amdgcn_mfma_f32_16x16x32_bf16(a[0], b, acc[0][nt], 0, 0, 0);
      acc[1][nt] = __builtin_amdgcn_mfma_f32_16x16x32_bf16(a[1], b, acc[1][nt], 0, 0, 0);
    }
  }
  // ---- int8 row quantization (C layout: row = rowBase+mt*16+q*4+r, col = nt*16+lm) ----
  #pragma unroll
  for (int mt = 0; mt < 2; mt++){
    #pragma unroll
    for (int r = 0; r < 4; r++){
      float rm = 0.f;
      #pragma unroll
      for (int nt = 0; nt < 8; nt++) rm = fmaxf(rm, fabsf(acc[mt][nt][r]));
      #pragma unroll
      for (int off = 1; off <= 8; off <<= 1) rm = fmaxf(rm, __shfl_xor(rm, off, 64));
      float qi = (rm > 0.f) ? 127.f/rm : 0.f;
      int lrow = wave*32 + mt*16 + q*4 + r;
      #pragma unroll
      for (int nt = 0; nt < 8; nt++)
        zq8[lrow][nt*16 + lm] = (char)(int)rintf(acc[mt][nt][r]*qi);
      long row = rowBase + mt*16 + q*4 + r;
      if (lm == 0 && row < M) sc_z[row] = rm * (1.f/127.f);
    }
  }
  // ---- fused attention row dots ----
  float as8[8], ad8[8];
  #pragma unroll
  for (int nt = 0; nt < 8; nt++){ as8[nt] = a_src[nt*16 + lm]; ad8[nt] = a_dst[nt*16 + lm]; }
  #pragma unroll
  for (int mt = 0; mt < 2; mt++){
    #pragma unroll
    for (int r = 0; r < 4; r++){
      float ps = 0.f, pd = 0.f;
      #pragma unroll
      for (int nt = 0; nt < 8; nt++){
        ps += acc[mt][nt][r] * as8[nt];
        pd += acc[mt][nt][r] * ad8[nt];
      }
      #pragma unroll
      for (int off = 1; off <= 8; off <<= 1){
        ps += __shfl_xor(ps, off, 64);
        pd += __shfl_xor(pd, off, 64);
      }
      long row = rowBase + mt*16 + q*4 + r;
      if (lm == 0 && row < M){
        attr[row] = make_float2(ps, dinv[row]);
        sdst[row] = pd;
      }
    }
  }
  __syncthreads();
  // ---- coalesced dump of int8 rows ----
  {
    int t = threadIdx.x;
    int lrow = t >> 1, half = t & 1;
    long row = (long)blockIdx.x*64 + lrow;
    if (row < M){
      uint4* dq = (uint4*)zq + row*8 + half*4;
      #pragma unroll
      for (int k = 0; k < 4; k++) dq[k] = zq8v[lrow][half*4 + k];
    }
  }
}

// ======= GAT aggregation: wave per node, 16 lanes/edge; int8 gather =======
__global__ __launch_bounds__(256) void k_agg0(const unsigned* __restrict__ zq,
                                              const float* __restrict__ sc_z,
                                              const int* __restrict__ rowp,
                                              const int2* __restrict__ col_sw,
                                              int2* __restrict__ col_ea,
                                              const float2* __restrict__ attr,
                                              const float* __restrict__ sdst_,
                                              const float* __restrict__ bias,
                                              ushort_t* __restrict__ out,
                                              unsigned* __restrict__ g0,
                                              float* __restrict__ scd0, int N){
  int n = blockIdx.x*4 + (threadIdx.x >> 6);
  if (n >= N) return;
  int l = threadIdx.x & 63;
  int rs = rowp[n], re = rowp[n+1];
  float2 an = attr[n];
  float sdd = sdst_[n];
  float es = an.x + sdd;
  es = (es >= 0.f) ? es : NEG_SLOPE*es;
  float pself = __expf(es);
  float ps = 0.f;
  for (int j = rs + l; j < re; j += 64){
    int2 sw = col_sw[j];
    float2 a = attr[sw.x];
    float ee = a.x + sdd;
    ee = (ee >= 0.f) ? ee : NEG_SLOPE*ee;
    float pe = __expf(ee);
    ps += pe;
    col_ea[j] = make_int2(sw.x, __float_as_int(pe * sc_z[sw.x]));
  }
  #pragma unroll
  for (int off = 32; off >= 1; off >>= 1) ps += __shfl_xor(ps, off, 64);
  float inv = 1.f / (ps + pself);

  int sub = l >> 4, q = l & 15;
  const uint2* f8 = (const uint2*)zq;
  float acc[8] = {0.f,0.f,0.f,0.f,0.f,0.f,0.f,0.f};
  for (int base = rs; base < re; base += 24){
    int2 p[6]; float a[6];
    #pragma unroll
    for (int j = 0; j < 6; j++){
      int e = base + sub + 4*j;
      int cc = min(e, re-1);
      p[j] = col_ea[cc];
      a[j] = (e < re) ? __int_as_float(p[j].y) : 0.f;
    }
    uint2 v[6];
    #pragma unroll
    for (int j = 0; j < 6; j++) v[j] = f8[(size_t)p[j].x*16 + q];
    #pragma unroll
    for (int j = 0; j < 6; j++) fma8q(acc, v[j], a[j]);
  }
  #pragma unroll
  for (int j = 0; j < 8; j++){
    acc[j] += __shfl_xor(acc[j], 16, 64);
    acc[j] += __shfl_xor(acc[j], 32, 64);
  }
  if (sub == 0){
    #pragma unroll
    for (int j = 0; j < 8; j++) acc[j] *= inv;
    fma8q(acc, f8[(size_t)n*16 + q], pself * inv * sc_z[n]);
    float4 b0 = ((const float4*)bias)[q*2];
    float4 b1 = ((const float4*)bias)[q*2 + 1];
    acc[0]+=b0.x; acc[1]+=b0.y; acc[2]+=b0.z; acc[3]+=b0.w;
    acc[4]+=b1.x; acc[5]+=b1.y; acc[6]+=b1.z; acc[7]+=b1.w;
    ((uint4*)out)[(size_t)n*16 + q] = pack8(acc);        // bf16 h0 for JK
    float rm = 0.f;
    #pragma unroll
    for (int j = 0; j < 8; j++) rm = fmaxf(rm, fabsf(acc[j]));
    #pragma unroll
    for (int off = 1; off <= 8; off <<= 1) rm = fmaxf(rm, __shfl_xor(rm, off, 64));
    float qi = (rm > 0.f) ? 127.f/rm : 0.f;
    ((uint2*)g0)[(size_t)n*16 + q] = packq8(acc, qi);
    if (l == 0) scd0[n] = rm * (1.f/127.f) * an.y;       // sc0 * dinv[n]
  }
}

// ======= per-layer edge coefficient prep: col_eq[e] = {src, w * scd_prev[src]} =======
// Streaming + L2-resident scalar gather (200KB table); removes the per-edge scd
// gather from the fagg inner loop (round-5's regression cause).
__global__ __launch_bounds__(256) void k_ecoef(const int2* __restrict__ col_sw,
                                               const float* __restrict__ scd,
                                               int2* __restrict__ col_eq, int E){
  int e = blockIdx.x*256 + threadIdx.x;
  if (e < E){
    int2 sw = col_sw[e];
    col_eq[e] = make_int2(sw.x, __float_as_int(__int_as_float(sw.y) * scd[sw.x]));
  }
}

// ======= fused GCN layer, int8 gather + precomputed coeff: h' = relu((A h) W + b) =======
// coeff per edge pre-folded in col_eq; acc scaled by dinv[n] once; self = scd_prev[n].
// MODE 1: write bf16 h' + int8 g' + scd'. MODE 2: last layer + JK max -> fp32 out.
template<int MODE>
__global__ __launch_bounds__(256) void k_fagg(const unsigned* __restrict__ gin,
                                              const float* __restrict__ scd_prev,
                                              const int* __restrict__ rowp,
                                              const int2* __restrict__ col_eq,
                                              const float* __restrict__ dinv,
                                              const ushort_t* __restrict__ Wl,
                                              const float* __restrict__ bias,
                                              ushort_t* __restrict__ out,
                                              unsigned* __restrict__ gout,
                                              float* __restrict__ scd_out,
                                              const ushort_t* __restrict__ j0,
                                              const ushort_t* __restrict__ j1,
                                              const ushort_t* __restrict__ j2,
                                              float* __restrict__ yout, int N){
  __shared__ ushort_t At[16][136];             // +8 pad: break LDS bank aliasing
  __shared__ uint4 q8v[16][8];                 // int8 output staging (16 x 128B)
  __shared__ unsigned rmaxs[16];
  char (*q8s)[128] = (char(*)[128])q8v;
  int wave = threadIdx.x >> 6, l = threadIdx.x & 63;
  int sub = l >> 4, q = l & 15;
  const uint2* f8 = (const uint2*)gin;
  int tile = blockIdx.x * 16;

  // ---- phase 1: aggregate 4 nodes per wave into LDS (bf16 rows) ----
  for (int i = 0; i < 4; i++){
    int row = wave*4 + i;
    int n = tile + row;
    int rs = 0, re = 0; float dn = 0.f, sprev = 0.f;
    if (n < N){ rs = rowp[n]; re = rowp[n+1]; dn = dinv[n]; sprev = scd_prev[n]; }
    float acc[8] = {0.f,0.f,0.f,0.f,0.f,0.f,0.f,0.f};
    for (int base = rs; base < re; base += 24){
      int2 p[6]; float a[6];
      #pragma unroll
      for (int j = 0; j < 6; j++){
        int e = base + sub + 4*j;
        int cc = min(e, re-1);
        p[j] = col_eq[cc];
        a[j] = (e < re) ? __int_as_float(p[j].y) : 0.f;
      }
      uint2 v[6];
      #pragma unroll
      for (int j = 0; j < 6; j++) v[j] = f8[(size_t)p[j].x*16 + q];
      #pragma unroll
      for (int j = 0; j < 6; j++) fma8q(acc, v[j], a[j]);
    }
    #pragma unroll
    for (int j = 0; j < 8; j++){
      acc[j] += __shfl_xor(acc[j], 16, 64);
      acc[j] += __shfl_xor(acc[j], 32, 64);
    }
    if (sub == 0){
      if (n < N) fma8q(acc, f8[(size_t)n*16 + q], sprev);   // self-loop term
      #pragma unroll
      for (int j = 0; j < 8; j++) acc[j] *= dn;             // hoisted dinv[n]
      *(uint4*)&At[row][q*8] = pack8(acc);                  // zeros for n >= N
    }
  }
  if (threadIdx.x < 16) rmaxs[threadIdx.x] = 0u;
  __syncthreads();

  // ---- phase 2: [16x128] @ [128x128] ; wave covers 32 output cols ----
  floatx4 co[2];
  co[0] = (floatx4){0.f,0.f,0.f,0.f};
  co[1] = (floatx4){0.f,0.f,0.f,0.f};
  #pragma unroll
  for (int kc = 0; kc < 4; kc++){
    int k0 = kc*32 + sub*8;
    short8 a = *(const short8*)&At[q][k0];
    #pragma unroll
    for (int ntl = 0; ntl < 2; ntl++){
      int nt = wave*2 + ntl;
      short8 b = *(const short8*)(Wl + (size_t)(nt*16 + q)*128 + k0);
      co[ntl] = __builtin_amdgcn_mfma_f32_16x16x32_bf16(a, b, co[ntl], 0, 0, 0);
    }
  }
  // C layout: col = lane&15 (=q), row = sub*4 + r
  float vv[4][2];
  #pragma unroll
  for (int r = 0; r < 4; r++){
    int row = sub*4 + r;
    int node = tile + row;
    float lmax = 0.f;
    #pragma unroll
    for (int ntl = 0; ntl < 2; ntl++){
      int colg = wave*32 + ntl*16 + q;
      float v = co[ntl][r] + bias[colg];
      v = fmaxf(v, 0.f);                       // all GCN layers ReLU'd
      vv[r][ntl] = v;
      lmax = fmaxf(lmax, v);
      if (node < N){
        size_t idx = (size_t)node*128 + colg;
        if (MODE == 1){
          out[idx] = f2b(v);                   // bf16 h' for JK
        } else {
          float m = fmaxf(fmaxf(b2f(j0[idx]), b2f(j1[idx])),
                          fmaxf(b2f(j2[idx]), v));
          yout[idx] = m;
        }
      }
    }
    if (MODE == 1) atomicMax(&rmaxs[row], __float_as_uint(lmax));  // v>=0: bits ordered
  }
  if (MODE == 1){
    __syncthreads();
    #pragma unroll
    for (int r = 0; r < 4; r++){
      int row = sub*4 + r;
      float rm = __uint_as_float(rmaxs[row]);
      float qi = (rm > 0.f) ? 127.f/rm : 0.f;
      #pragma unroll
      for (int ntl = 0; ntl < 2; ntl++){
        int colg = wave*32 + ntl*16 + q;
        q8s[row][colg] = (char)(int)rintf(vv[r][ntl]*qi);
      }
    }
    if (threadIdx.x < 16){
      int node = tile + threadIdx.x;
      if (node < N){
        float rm = __uint_as_float(rmaxs[threadIdx.x]);
        scd_out[node] = rm * (1.f/127.f) * dinv[node];
      }
    }
    __syncthreads();
    if (threadIdx.x < 128){
      int row = threadIdx.x >> 3, c = threadIdx.x & 7;
      int node = tile + row;
      if (node < N) ((uint4*)gout)[(size_t)node*8 + c] = q8v[row][c];
    }
  }
}

extern "C" void kernel_launch(void* const* d_in, const int* in_sizes, int n_in,
                              void* d_out, int out_size, void* d_ws, size_t ws_size,
                              hipStream_t stream){
  const float* x      = (const float*)d_in[0];
  const int*   eidx   = (const int*)d_in[1];
  const float* emask  = (const float*)d_in[2];
  const float* W_gat  = (const float*)d_in[3];
  const float* a_src  = (const float*)d_in[4];
  const float* a_dst  = (const float*)d_in[5];
  const float* b_gat  = (const float*)d_in[6];
  const float* W_gcn  = (const float*)d_in[7];
  const float* b_gcn  = (const float*)d_in[8];
  int N = in_sizes[0] / HIDDEN;
  int E = in_sizes[1] / 2;
  const int* src = eidx;
  const int* dst = eidx + E;

  char* p = (char*)d_ws;
  auto carve = [&](size_t bytes)->char*{ char* q = p; p += align_up(bytes, 512); return q; };
  ushort_t* h0   = (ushort_t*)carve((size_t)N*HIDDEN*2);
  ushort_t* h1   = (ushort_t*)carve((size_t)N*HIDDEN*2);
  ushort_t* h2   = (ushort_t*)carve((size_t)N*HIDDEN*2);
  ushort_t* Wt   = (ushort_t*)carve((size_t)4*HIDDEN*HIDDEN*2);
  unsigned* zq   = (unsigned*)carve((size_t)N*HIDDEN);      // int8 matrices (128B rows)
  unsigned* g0q  = (unsigned*)carve((size_t)N*HIDDEN);
  unsigned* g1q  = (unsigned*)carve((size_t)N*HIDDEN);
  unsigned* g2q  = (unsigned*)carve((size_t)N*HIDDEN);
  float* sc_z    = (float*)carve((size_t)N*4);
  float* scd0    = (float*)carve((size_t)N*4);
  float* scd1    = (float*)carve((size_t)N*4);
  float* scd2    = (float*)carve((size_t)N*4);
  float2* attr   = (float2*)carve((size_t)N*8);
  float* sdst    = (float*)carve((size_t)N*4);
  float* dinv    = (float*)carve((size_t)N*4);
  int*   rowp    = (int*)  carve((size_t)(N+1)*4);
  int2*  col_sw  = (int2*) carve((size_t)E*8);
  int2*  col_ea  = (int2*) carve((size_t)E*8);    // GAT exp stream, reused as col_eq
  int2*  tpw     = (int2*) carve((size_t)E*8);
  int nbkt = (N + 255) >> 8;                       // 196
  int M    = nbkt * P_SORT;                        // 50176
  int*   bcnt  = (int*)carve((size_t)M*4);
  int*   incl  = (int*)carve((size_t)M*4);
  int nbs = (M + 255) / 256;                       // == nbkt
  int*   blockSums = (int*)carve((size_t)nbs*4);
  int*   blockOffs = (int*)carve((size_t)nbs*4);
  (void)ws_size; (void)n_in; (void)out_size;

  int epb = (E + P_SORT - 1) / P_SORT;
  int gb  = (N + 63) / 64;
  int nwb = (N + 3) / 4;
  int nfb = (N + 15) / 16;
  int neb = (E + 255) / 256;

  // CSR build (atomic-free, full-chip); cast rides along in extra blocks
  k_b1cnt_cast<<<P_SORT + 256, 256, 0, stream>>>(dst, bcnt, W_gat, W_gcn, Wt, E, epb, nbkt);
  k_scan1  <<<nbs, 256, 0, stream>>>(bcnt, incl, blockSums, M);
  k_scan2  <<<1,   256, 0, stream>>>(blockSums, blockOffs, nbs);
  k_b1place<<<P_SORT, 256, 0, stream>>>(src, dst, emask, incl, bcnt, blockOffs,
                                        tpw, E, epb, nbkt);
  k_b2     <<<nbkt, 256, 0, stream>>>(tpw, blockOffs, col_sw, rowp, dinv, N, E, nbkt);

  // xp = x @ W_gat -> int8 rows + scales + fused attention dots
  k_gemm1<<<gb, 128, 0, stream>>>(x, Wt, zq, sc_z, a_src, a_dst, dinv, attr, sdst, N);

  // GAT aggregation (int8 gather), produces h0 bf16 + g0 int8 + scd0
  k_agg0<<<nwb, 256, 0, stream>>>(zq, sc_z, rowp, col_sw, col_ea, attr, sdst,
                                  b_gat, h0, g0q, scd0, N);

  // fused GCN layers: h' = relu((A h) W + b), coeff streams precomputed per layer
  k_ecoef<<<neb, 256, 0, stream>>>(col_sw, scd0, col_ea, E);
  k_fagg<1><<<nfb, 256, 0, stream>>>(g0q, scd0, rowp, col_ea, dinv,
                                     Wt + (size_t)1*16384, b_gcn + 0,
                                     h1, g1q, scd1,
                                     nullptr, nullptr, nullptr, nullptr, N);
  k_ecoef<<<neb, 256, 0, stream>>>(col_sw, scd1, col_ea, E);
  k_fagg<1><<<nfb, 256, 0, stream>>>(g1q, scd1, rowp, col_ea, dinv,
                                     Wt + (size_t)2*16384, b_gcn + 128,
                                     h2, g2q, scd2,
                                     nullptr, nullptr, nullptr, nullptr, N);
  k_ecoef<<<neb, 256, 0, stream>>>(col_sw, scd2, col_ea, E);
  // last layer + fused JK max over {h0, h1, h2, h3} -> fp32 d_out
  k_fagg<2><<<nfb, 256, 0, stream>>>(g2q, scd2, rowp, col_ea, dinv,
                                     Wt + (size_t)3*16384, b_gcn + 256,
                                     nullptr, nullptr, nullptr,
                                     h0, h1, h2, (float*)d_out, N);
}

// Round 7
// 345.007 us; speedup vs baseline: 1.1385x; 1.0045x over previous
//
#include <hip/hip_runtime.h>

#define HIDDEN 128
#define NEG_SLOPE 0.2f
#define P_SORT 256          // blocks for phase-1 bucket sort

typedef unsigned short ushort_t;
typedef __attribute__((ext_vector_type(8))) short short8;
typedef __attribute__((ext_vector_type(4))) float floatx4;

static inline size_t align_up(size_t x, size_t a){ return (x + a - 1) & ~(a - 1); }

__device__ __forceinline__ ushort_t f2b(float f){
  unsigned u = __float_as_uint(f);
  unsigned r = (u + 0x7FFFu + ((u >> 16) & 1u)) >> 16;
  return (ushort_t)r;
}

__device__ __forceinline__ float b2f(ushort_t u){
  return __uint_as_float(((unsigned)u) << 16);
}

// int8 row-quantized feature FMA: 8 sbytes in a uint2, coeff a already includes row scale
__device__ __forceinline__ void fma8q(float* acc, uint2 v, float a){
  int x = (int)v.x, y = (int)v.y;
  acc[0] += a * (float)((x << 24) >> 24);
  acc[1] += a * (float)((x << 16) >> 24);
  acc[2] += a * (float)((x <<  8) >> 24);
  acc[3] += a * (float)( x        >> 24);
  acc[4] += a * (float)((y << 24) >> 24);
  acc[5] += a * (float)((y << 16) >> 24);
  acc[6] += a * (float)((y <<  8) >> 24);
  acc[7] += a * (float)( y        >> 24);
}

__device__ __forceinline__ uint2 packq8(const float* f, float qi){
  unsigned a = 0, b = 0;
  int q;
  q = (int)rintf(f[0]*qi); a |= ((unsigned)q & 255u);
  q = (int)rintf(f[1]*qi); a |= ((unsigned)q & 255u) << 8;
  q = (int)rintf(f[2]*qi); a |= ((unsigned)q & 255u) << 16;
  q = (int)rintf(f[3]*qi); a |= ((unsigned)q & 255u) << 24;
  q = (int)rintf(f[4]*qi); b |= ((unsigned)q & 255u);
  q = (int)rintf(f[5]*qi); b |= ((unsigned)q & 255u) << 8;
  q = (int)rintf(f[6]*qi); b |= ((unsigned)q & 255u) << 16;
  q = (int)rintf(f[7]*qi); b |= ((unsigned)q & 255u) << 24;
  uint2 r; r.x = a; r.y = b; return r;
}

__device__ __forceinline__ uint4 pack8(const float* f){
  uint4 u;
  u.x = (unsigned)f2b(f[0]) | ((unsigned)f2b(f[1]) << 16);
  u.y = (unsigned)f2b(f[2]) | ((unsigned)f2b(f[3]) << 16);
  u.z = (unsigned)f2b(f[4]) | ((unsigned)f2b(f[5]) << 16);
  u.w = (unsigned)f2b(f[6]) | ((unsigned)f2b(f[7]) << 16);
  return u;
}

// ============ CSR build: two-pass bucketed counting sort ============
// merged: blocks [0, P_SORT) do the bucket count; blocks [P_SORT, P_SORT+256)
// do the independent weight cast (4 mats fp32 -> transposed bf16).

__global__ __launch_bounds__(256) void k_b1cnt_cast(const int* __restrict__ dst,
                                                    int* __restrict__ bcnt,
                                                    const float* __restrict__ Wg,
                                                    const float* __restrict__ Wc,
                                                    ushort_t* __restrict__ Wt,
                                                    int E, int epb, int nbkt){
  int t = threadIdx.x;
  if (blockIdx.x >= P_SORT){
    int i = (blockIdx.x - P_SORT)*256 + t;     // 4*16384 elements
    int mat = i >> 14, idx = i & 16383;
    int k = idx >> 7, n = idx & 127;
    float v = (mat == 0) ? Wg[idx] : Wc[(mat-1)*16384 + idx];
    Wt[mat*16384 + n*128 + k] = f2b(v);
    return;
  }
  __shared__ unsigned c[256];
  c[t] = 0;
  __syncthreads();
  int e0 = blockIdx.x * epb;
  int e1 = min(E, e0 + epb);
  for (int e = e0 + t; e < e1; e += 256) atomicAdd(&c[dst[e] >> 8], 1u);
  __syncthreads();
  if (t < nbkt) bcnt[t * P_SORT + blockIdx.x] = (int)c[t];
}

__global__ void k_scan1(const int* __restrict__ in, int* __restrict__ incl,
                        int* __restrict__ blockSums, int M){
  __shared__ int sd[256];
  int t = threadIdx.x;
  int i = blockIdx.x*256 + t;
  int v = (i < M) ? in[i] : 0;
  sd[t] = v; __syncthreads();
  for (int off = 1; off < 256; off <<= 1){
    int add = (t >= off) ? sd[t-off] : 0;
    __syncthreads();
    sd[t] += add;
    __syncthreads();
  }
  if (i < M) incl[i] = sd[t];
  if (t == 255) blockSums[blockIdx.x] = sd[255];
}

__global__ void k_scan2(const int* __restrict__ blockSums, int* __restrict__ blockOffs, int nb){
  __shared__ int sd[256];
  __shared__ int carry;
  int t = threadIdx.x;
  if (t == 0) carry = 0;
  __syncthreads();
  for (int base = 0; base < nb; base += 256){
    int i = base + t;
    int v = (i < nb) ? blockSums[i] : 0;
    sd[t] = v; __syncthreads();
    for (int off = 1; off < 256; off <<= 1){
      int add = (t >= off) ? sd[t-off] : 0;
      __syncthreads();
      sd[t] += add;
      __syncthreads();
    }
    if (i < nb) blockOffs[i] = carry + sd[t] - v;
    __syncthreads();
    if (t == 0) carry += sd[255];
    __syncthreads();
  }
}

// phase-1 scatter: per-(bucket,block) base rebuilt in LDS from incl/bcnt/blockOffs
__global__ __launch_bounds__(256) void k_b1place(const int* __restrict__ src,
                                                 const int* __restrict__ dst,
                                                 const float* __restrict__ w,
                                                 const int* __restrict__ incl,
                                                 const int* __restrict__ bcnt,
                                                 const int* __restrict__ blockOffs,
                                                 int2* __restrict__ tpw,
                                                 int E, int epb, int nbkt){
  __shared__ int base_[256];
  __shared__ unsigned c[256];
  int t = threadIdx.x;
  c[t] = 0;
  if (t < nbkt){
    int idx = t * P_SORT + blockIdx.x;
    base_[t] = incl[idx] - bcnt[idx] + blockOffs[t];
  }
  __syncthreads();
  int e0 = blockIdx.x * epb;
  int e1 = min(E, e0 + epb);
  for (int e = e0 + t; e < e1; e += 256){
    int d = dst[e];
    int b = d >> 8;
    unsigned r = atomicAdd(&c[b], 1u);
    int pos = base_[b] + (int)r;
    tpw[pos] = make_int2((int)((unsigned)src[e] | ((unsigned)(d & 255) << 16)),
                         __float_as_int(w[e]));
  }
}

// phase-2 fine sort: counting sort on key (row, src>>12)
__global__ __launch_bounds__(256) void k_b2(const int2* __restrict__ tpw,
                                            const int* __restrict__ blockOffs,
                                            int2* __restrict__ col_sw,
                                            int* __restrict__ rowp,
                                            float* __restrict__ dinv,
                                            int N, int E, int nbkt){
  __shared__ int cnt[4096];      // 256 rows x 16 src-slices
  __shared__ int tsum[256];
  __shared__ float wsum[256];
  int b = blockIdx.x, t = threadIdx.x;
  int e0 = blockOffs[b];
  int e1 = (b + 1 < nbkt) ? blockOffs[b + 1] : E;
  #pragma unroll
  for (int i = 0; i < 16; i++) cnt[t*16 + i] = 0;
  wsum[t] = 0.f;
  __syncthreads();
  for (int e = e0 + t; e < e1; e += 256){
    int2 pw = tpw[e];
    unsigned dl = ((unsigned)pw.x >> 16) & 255u;
    unsigned s  = ((unsigned)pw.x & 0xFFFFu) >> 12;     // src slice 0..15
    atomicAdd(&cnt[(dl << 4) | s], 1);
  }
  __syncthreads();
  int loc[16]; int run = 0;
  #pragma unroll
  for (int i = 0; i < 16; i++){ loc[i] = run; run += cnt[t*16 + i]; }
  tsum[t] = run;
  __syncthreads();
  for (int off = 1; off < 256; off <<= 1){
    int add = (t >= off) ? tsum[t-off] : 0;
    __syncthreads();
    tsum[t] += add;
    __syncthreads();
  }
  int base = tsum[t] - run;                              // exclusive over rows
  #pragma unroll
  for (int i = 0; i < 16; i++) cnt[t*16 + i] = base + loc[i];
  int node = b*256 + t;
  if (node < N) rowp[node] = e0 + base;
  if (b == 0 && t == 0) rowp[N] = E;
  __syncthreads();
  for (int e = e0 + t; e < e1; e += 256){
    int2 pw = tpw[e];
    unsigned dl = ((unsigned)pw.x >> 16) & 255u;
    unsigned srcv = (unsigned)pw.x & 0xFFFFu;
    unsigned s = srcv >> 12;
    int pos = e0 + atomicAdd(&cnt[(dl << 4) | s], 1);    // old value == slot
    col_sw[pos] = make_int2((int)srcv, pw.y);
    atomicAdd(&wsum[dl], __int_as_float(pw.y));
  }
  __syncthreads();
  if (node < N) dinv[node] = rsqrtf(wsum[t] + 1.0f);     // +1 = self-loop weight
}

// ------- MFMA GEMM (GAT layer): xp = x @ W_gat; outputs int8-quantized xp rows
// (zq), packed per-row table attr4 = {a_src dot, dinv, int8 scale, 0}, and sdst. -------
__global__ __launch_bounds__(128) void k_gemm1(const float* __restrict__ Ain,
                                               const ushort_t* __restrict__ Wt,
                                               unsigned* __restrict__ zq,   // N*32B (uint)
                                               const float* __restrict__ a_src,
                                               const float* __restrict__ a_dst,
                                               const float* __restrict__ dinv,
                                               float4* __restrict__ attr4,
                                               float* __restrict__ sdst, int M){
  __shared__ uint4 zq8v[64][8];                 // 64 rows x 128B int8 staging
  char (*zq8)[128] = (char(*)[128])zq8v;
  int wave = threadIdx.x >> 6, l = threadIdx.x & 63;
  int q = l >> 4, lm = l & 15;
  int rowBase = blockIdx.x*64 + wave*32;
  floatx4 acc[2][8];
  #pragma unroll
  for (int mt = 0; mt < 2; mt++)
    #pragma unroll
    for (int nt = 0; nt < 8; nt++) acc[mt][nt] = (floatx4){0.f,0.f,0.f,0.f};

  #pragma unroll
  for (int kc = 0; kc < 4; kc++){
    int k0 = kc*32 + q*8;
    short8 a[2];
    #pragma unroll
    for (int mt = 0; mt < 2; mt++){
      long r = rowBase + mt*16 + lm;
      if (r < M){
        const float* ap = Ain + r*128 + k0;
        float4 u = *(const float4*)ap;
        float4 v = *(const float4*)(ap + 4);
        short8 tv;
        tv[0]=(short)f2b(u.x); tv[1]=(short)f2b(u.y); tv[2]=(short)f2b(u.z); tv[3]=(short)f2b(u.w);
        tv[4]=(short)f2b(v.x); tv[5]=(short)f2b(v.y); tv[6]=(short)f2b(v.z); tv[7]=(short)f2b(v.w);
        a[mt] = tv;
      } else a[mt] = (short8){0,0,0,0,0,0,0,0};
    }
    #pragma unroll
    for (int nt = 0; nt < 8; nt++){
      short8 b = *(const short8*)(Wt + (nt*16 + lm)*128 + k0);
      acc[0][nt] = __builtin_amdgcn_mfma_f32_16x16x32_bf16(a[0], b, acc[0][nt], 0, 0, 0);
      acc[1][nt] = __builtin_amdgcn_mfma_f32_16x16x32_bf16(a[1], b, acc[1][nt], 0, 0, 0);
    }
  }
  // ---- int8 row quantization (C layout: row = rowBase+mt*16+q*4+r, col = nt*16+lm) ----
  float rms[2][4];
  #pragma unroll
  for (int mt = 0; mt < 2; mt++){
    #pragma unroll
    for (int r = 0; r < 4; r++){
      float rm = 0.f;
      #pragma unroll
      for (int nt = 0; nt < 8; nt++) rm = fmaxf(rm, fabsf(acc[mt][nt][r]));
      #pragma unroll
      for (int off = 1; off <= 8; off <<= 1) rm = fmaxf(rm, __shfl_xor(rm, off, 64));
      float qi = (rm > 0.f) ? 127.f/rm : 0.f;
      int lrow = wave*32 + mt*16 + q*4 + r;
      #pragma unroll
      for (int nt = 0; nt < 8; nt++)
        zq8[lrow][nt*16 + lm] = (char)(int)rintf(acc[mt][nt][r]*qi);
      rms[mt][r] = rm * (1.f/127.f);
    }
  }
  // ---- fused attention row dots ----
  float as8[8], ad8[8];
  #pragma unroll
  for (int nt = 0; nt < 8; nt++){ as8[nt] = a_src[nt*16 + lm]; ad8[nt] = a_dst[nt*16 + lm]; }
  #pragma unroll
  for (int mt = 0; mt < 2; mt++){
    #pragma unroll
    for (int r = 0; r < 4; r++){
      float ps = 0.f, pd = 0.f;
      #pragma unroll
      for (int nt = 0; nt < 8; nt++){
        ps += acc[mt][nt][r] * as8[nt];
        pd += acc[mt][nt][r] * ad8[nt];
      }
      #pragma unroll
      for (int off = 1; off <= 8; off <<= 1){
        ps += __shfl_xor(ps, off, 64);
        pd += __shfl_xor(pd, off, 64);
      }
      long row = rowBase + mt*16 + q*4 + r;
      if (lm == 0 && row < M){
        attr4[row] = make_float4(ps, dinv[row], rms[mt][r], 0.f);
        sdst[row] = pd;
      }
    }
  }
  __syncthreads();
  // ---- coalesced dump of int8 rows ----
  {
    int t = threadIdx.x;
    int lrow = t >> 1, half = t & 1;
    long row = (long)blockIdx.x*64 + lrow;
    if (row < M){
      uint4* dq = (uint4*)zq + row*8 + half*4;
      #pragma unroll
      for (int k = 0; k < 4; k++) dq[k] = zq8v[lrow][half*4 + k];
    }
  }
}

// ======= GAT aggregation, single fused sweep: wave per node, 16 lanes/edge =======
// Per edge slot: col -> {attr4 broadcast (L2), int8 feature (HBM)} in parallel.
// exp computed redundantly per slot; softmax denom reduced across slots at end;
// 1/denom applied to acc after. No col_ea stream.
__global__ __launch_bounds__(256) void k_agg0(const unsigned* __restrict__ zq,
                                              const int* __restrict__ rowp,
                                              const int2* __restrict__ col_sw,
                                              const float4* __restrict__ attr4,
                                              const float* __restrict__ sdst_,
                                              const float* __restrict__ bias,
                                              ushort_t* __restrict__ out,
                                              unsigned* __restrict__ g0,
                                              float* __restrict__ scd0, int N){
  int n = blockIdx.x*4 + (threadIdx.x >> 6);
  if (n >= N) return;
  int l = threadIdx.x & 63;
  int sub = l >> 4, q = l & 15;
  int rs = rowp[n], re = rowp[n+1];
  float4 an = attr4[n];
  float sdd = sdst_[n];
  float es = an.x + sdd;
  es = (es >= 0.f) ? es : NEG_SLOPE*es;
  float pself = __expf(es);

  const uint2* f8 = (const uint2*)zq;
  float acc[8] = {0.f,0.f,0.f,0.f,0.f,0.f,0.f,0.f};
  float ps = 0.f;
  int last = (re > rs) ? re - 1 : 0;
  for (int base = rs; base < re; base += 24){
    int2 p[6];
    #pragma unroll
    for (int j = 0; j < 6; j++){
      int e = base + sub + 4*j;
      p[j] = col_sw[min(e, last)];
    }
    float4 at[6];
    #pragma unroll
    for (int j = 0; j < 6; j++) at[j] = attr4[p[j].x];   // 16-lane broadcast, L2
    uint2 v[6];
    #pragma unroll
    for (int j = 0; j < 6; j++) v[j] = f8[(size_t)p[j].x*16 + q];
    #pragma unroll
    for (int j = 0; j < 6; j++){
      int e = base + sub + 4*j;
      float ee = at[j].x + sdd;
      ee = (ee >= 0.f) ? ee : NEG_SLOPE*ee;
      float pe = (e < re) ? __expf(ee) : 0.f;
      ps += pe;
      fma8q(acc, v[j], pe * at[j].z);
    }
  }
  // softmax denom: each slot's 16 lanes hold identical slot-sum; combine 4 slots
  ps += __shfl_xor(ps, 16, 64);
  ps += __shfl_xor(ps, 32, 64);
  float inv = 1.f / (ps + pself);
  #pragma unroll
  for (int j = 0; j < 8; j++){
    acc[j] += __shfl_xor(acc[j], 16, 64);
    acc[j] += __shfl_xor(acc[j], 32, 64);
  }
  if (sub == 0){
    #pragma unroll
    for (int j = 0; j < 8; j++) acc[j] *= inv;
    fma8q(acc, f8[(size_t)n*16 + q], pself * inv * an.z);
    float4 b0 = ((const float4*)bias)[q*2];
    float4 b1 = ((const float4*)bias)[q*2 + 1];
    acc[0]+=b0.x; acc[1]+=b0.y; acc[2]+=b0.z; acc[3]+=b0.w;
    acc[4]+=b1.x; acc[5]+=b1.y; acc[6]+=b1.z; acc[7]+=b1.w;
    ((uint4*)out)[(size_t)n*16 + q] = pack8(acc);        // bf16 h0 for JK
    float rm = 0.f;
    #pragma unroll
    for (int j = 0; j < 8; j++) rm = fmaxf(rm, fabsf(acc[j]));
    #pragma unroll
    for (int off = 1; off <= 8; off <<= 1) rm = fmaxf(rm, __shfl_xor(rm, off, 64));
    float qi = (rm > 0.f) ? 127.f/rm : 0.f;
    ((uint2*)g0)[(size_t)n*16 + q] = packq8(acc, qi);
    if (l == 0) scd0[n] = rm * (1.f/127.f) * an.y;       // sc0 * dinv[n]
  }
}

// ======= per-layer edge coefficient prep: col_eq[e] = {src, w * scd_prev[src]} =======
__global__ __launch_bounds__(256) void k_ecoef(const int2* __restrict__ col_sw,
                                               const float* __restrict__ scd,
                                               int2* __restrict__ col_eq, int E){
  int e = blockIdx.x*256 + threadIdx.x;
  if (e < E){
    int2 sw = col_sw[e];
    col_eq[e] = make_int2(sw.x, __float_as_int(__int_as_float(sw.y) * scd[sw.x]));
  }
}

// ======= fused GCN layer, int8 gather + precomputed coeff: h' = relu((A h) W + b) =======
// Phase 1 INTERLEAVES 2 node-chains per wave (issue both nodes' col loads, then both
// feature batches, then two independent FMA chains) -> wave critical path halves.
// MODE 1: write bf16 h' + int8 g' + scd'. MODE 2: last layer + JK max -> fp32 out.
template<int MODE>
__global__ __launch_bounds__(256) void k_fagg(const unsigned* __restrict__ gin,
                                              const float* __restrict__ scd_prev,
                                              const int* __restrict__ rowp,
                                              const int2* __restrict__ col_eq,
                                              const float* __restrict__ dinv,
                                              const ushort_t* __restrict__ Wl,
                                              const float* __restrict__ bias,
                                              ushort_t* __restrict__ out,
                                              unsigned* __restrict__ gout,
                                              float* __restrict__ scd_out,
                                              const ushort_t* __restrict__ j0,
                                              const ushort_t* __restrict__ j1,
                                              const ushort_t* __restrict__ j2,
                                              float* __restrict__ yout, int N){
  __shared__ ushort_t At[16][136];             // +8 pad: break LDS bank aliasing
  __shared__ uint4 q8v[16][8];                 // int8 output staging (16 x 128B)
  __shared__ unsigned rmaxs[16];
  char (*q8s)[128] = (char(*)[128])q8v;
  int wave = threadIdx.x >> 6, l = threadIdx.x & 63;
  int sub = l >> 4, q = l & 15;
  const uint2* f8 = (const uint2*)gin;
  int tile = blockIdx.x * 16;

  // ---- phase 1: 4 nodes per wave, processed as 2 interleaved pairs ----
  #pragma unroll
  for (int pair = 0; pair < 2; pair++){
    int rowA = wave*4 + pair*2, rowB = rowA + 1;
    int nA = tile + rowA, nB = tile + rowB;
    int rsA = 0, reA = 0, rsB = 0, reB = 0;
    float dnA = 0.f, spA = 0.f, dnB = 0.f, spB = 0.f;
    if (nA < N){ rsA = rowp[nA]; reA = rowp[nA+1]; dnA = dinv[nA]; spA = scd_prev[nA]; }
    if (nB < N){ rsB = rowp[nB]; reB = rowp[nB+1]; dnB = dinv[nB]; spB = scd_prev[nB]; }
    int lastA = (reA > rsA) ? reA - 1 : 0;
    int lastB = (reB > rsB) ? reB - 1 : 0;
    float accA[8] = {0.f,0.f,0.f,0.f,0.f,0.f,0.f,0.f};
    float accB[8] = {0.f,0.f,0.f,0.f,0.f,0.f,0.f,0.f};
    int baseA = rsA, baseB = rsB;
    while (baseA < reA || baseB < reB){
      int2 pA[6], pB[6];
      #pragma unroll
      for (int j = 0; j < 6; j++){
        int e = baseA + sub + 4*j;
        pA[j] = col_eq[min(e, lastA)];
      }
      #pragma unroll
      for (int j = 0; j < 6; j++){
        int e = baseB + sub + 4*j;
        pB[j] = col_eq[min(e, lastB)];
      }
      uint2 vA[6], vB[6];
      #pragma unroll
      for (int j = 0; j < 6; j++) vA[j] = f8[(size_t)pA[j].x*16 + q];
      #pragma unroll
      for (int j = 0; j < 6; j++) vB[j] = f8[(size_t)pB[j].x*16 + q];
      #pragma unroll
      for (int j = 0; j < 6; j++){
        int e = baseA + sub + 4*j;
        fma8q(accA, vA[j], (e < reA) ? __int_as_float(pA[j].y) : 0.f);
      }
      #pragma unroll
      for (int j = 0; j < 6; j++){
        int e = baseB + sub + 4*j;
        fma8q(accB, vB[j], (e < reB) ? __int_as_float(pB[j].y) : 0.f);
      }
      baseA += 24; baseB += 24;
    }
    #pragma unroll
    for (int j = 0; j < 8; j++){
      accA[j] += __shfl_xor(accA[j], 16, 64);
      accA[j] += __shfl_xor(accA[j], 32, 64);
      accB[j] += __shfl_xor(accB[j], 16, 64);
      accB[j] += __shfl_xor(accB[j], 32, 64);
    }
    if (sub == 0){
      if (nA < N) fma8q(accA, f8[(size_t)nA*16 + q], spA);   // self-loop term
      #pragma unroll
      for (int j = 0; j < 8; j++) accA[j] *= dnA;            // hoisted dinv
      *(uint4*)&At[rowA][q*8] = pack8(accA);                 // zeros for n >= N
      if (nB < N) fma8q(accB, f8[(size_t)nB*16 + q], spB);
      #pragma unroll
      for (int j = 0; j < 8; j++) accB[j] *= dnB;
      *(uint4*)&At[rowB][q*8] = pack8(accB);
    }
  }
  if (threadIdx.x < 16) rmaxs[threadIdx.x] = 0u;
  __syncthreads();

  // ---- phase 2: [16x128] @ [128x128] ; wave covers 32 output cols ----
  floatx4 co[2];
  co[0] = (floatx4){0.f,0.f,0.f,0.f};
  co[1] = (floatx4){0.f,0.f,0.f,0.f};
  #pragma unroll
  for (int kc = 0; kc < 4; kc++){
    int k0 = kc*32 + sub*8;
    short8 a = *(const short8*)&At[q][k0];
    #pragma unroll
    for (int ntl = 0; ntl < 2; ntl++){
      int nt = wave*2 + ntl;
      short8 b = *(const short8*)(Wl + (size_t)(nt*16 + q)*128 + k0);
      co[ntl] = __builtin_amdgcn_mfma_f32_16x16x32_bf16(a, b, co[ntl], 0, 0, 0);
    }
  }
  // C layout: col = lane&15 (=q), row = sub*4 + r
  float vv[4][2];
  #pragma unroll
  for (int r = 0; r < 4; r++){
    int row = sub*4 + r;
    int node = tile + row;
    float lmax = 0.f;
    #pragma unroll
    for (int ntl = 0; ntl < 2; ntl++){
      int colg = wave*32 + ntl*16 + q;
      float v = co[ntl][r] + bias[colg];
      v = fmaxf(v, 0.f);                       // all GCN layers ReLU'd
      vv[r][ntl] = v;
      lmax = fmaxf(lmax, v);
      if (node < N){
        size_t idx = (size_t)node*128 + colg;
        if (MODE == 1){
          out[idx] = f2b(v);                   // bf16 h' for JK
        } else {
          float m = fmaxf(fmaxf(b2f(j0[idx]), b2f(j1[idx])),
                          fmaxf(b2f(j2[idx]), v));
          yout[idx] = m;
        }
      }
    }
    if (MODE == 1) atomicMax(&rmaxs[row], __float_as_uint(lmax));  // v>=0: bits ordered
  }
  if (MODE == 1){
    __syncthreads();
    #pragma unroll
    for (int r = 0; r < 4; r++){
      int row = sub*4 + r;
      float rm = __uint_as_float(rmaxs[row]);
      float qi = (rm > 0.f) ? 127.f/rm : 0.f;
      #pragma unroll
      for (int ntl = 0; ntl < 2; ntl++){
        int colg = wave*32 + ntl*16 + q;
        q8s[row][colg] = (char)(int)rintf(vv[r][ntl]*qi);
      }
    }
    if (threadIdx.x < 16){
      int node = tile + threadIdx.x;
      if (node < N){
        float rm = __uint_as_float(rmaxs[threadIdx.x]);
        scd_out[node] = rm * (1.f/127.f) * dinv[node];
      }
    }
    __syncthreads();
    if (threadIdx.x < 128){
      int row = threadIdx.x >> 3, c = threadIdx.x & 7;
      int node = tile + row;
      if (node < N) ((uint4*)gout)[(size_t)node*8 + c] = q8v[row][c];
    }
  }
}

extern "C" void kernel_launch(void* const* d_in, const int* in_sizes, int n_in,
                              void* d_out, int out_size, void* d_ws, size_t ws_size,
                              hipStream_t stream){
  const float* x      = (const float*)d_in[0];
  const int*   eidx   = (const int*)d_in[1];
  const float* emask  = (const float*)d_in[2];
  const float* W_gat  = (const float*)d_in[3];
  const float* a_src  = (const float*)d_in[4];
  const float* a_dst  = (const float*)d_in[5];
  const float* b_gat  = (const float*)d_in[6];
  const float* W_gcn  = (const float*)d_in[7];
  const float* b_gcn  = (const float*)d_in[8];
  int N = in_sizes[0] / HIDDEN;
  int E = in_sizes[1] / 2;
  const int* src = eidx;
  const int* dst = eidx + E;

  char* p = (char*)d_ws;
  auto carve = [&](size_t bytes)->char*{ char* q = p; p += align_up(bytes, 512); return q; };
  ushort_t* h0   = (ushort_t*)carve((size_t)N*HIDDEN*2);
  ushort_t* h1   = (ushort_t*)carve((size_t)N*HIDDEN*2);
  ushort_t* h2   = (ushort_t*)carve((size_t)N*HIDDEN*2);
  ushort_t* Wt   = (ushort_t*)carve((size_t)4*HIDDEN*HIDDEN*2);
  unsigned* zq   = (unsigned*)carve((size_t)N*HIDDEN);      // int8 matrices (128B rows)
  unsigned* g0q  = (unsigned*)carve((size_t)N*HIDDEN);
  unsigned* g1q  = (unsigned*)carve((size_t)N*HIDDEN);
  unsigned* g2q  = (unsigned*)carve((size_t)N*HIDDEN);
  float* scd0    = (float*)carve((size_t)N*4);
  float* scd1    = (float*)carve((size_t)N*4);
  float* scd2    = (float*)carve((size_t)N*4);
  float4* attr4  = (float4*)carve((size_t)N*16);
  float* sdst    = (float*)carve((size_t)N*4);
  float* dinv    = (float*)carve((size_t)N*4);
  int*   rowp    = (int*)  carve((size_t)(N+1)*4);
  int2*  col_sw  = (int2*) carve((size_t)E*8);
  int2*  col_eq  = (int2*) carve((size_t)E*8);
  int2*  tpw     = (int2*) carve((size_t)E*8);
  int nbkt = (N + 255) >> 8;                       // 196
  int M    = nbkt * P_SORT;                        // 50176
  int*   bcnt  = (int*)carve((size_t)M*4);
  int*   incl  = (int*)carve((size_t)M*4);
  int nbs = (M + 255) / 256;                       // == nbkt
  int*   blockSums = (int*)carve((size_t)nbs*4);
  int*   blockOffs = (int*)carve((size_t)nbs*4);
  (void)ws_size; (void)n_in; (void)out_size;

  int epb = (E + P_SORT - 1) / P_SORT;
  int gb  = (N + 63) / 64;
  int nwb = (N + 3) / 4;
  int nfb = (N + 15) / 16;
  int neb = (E + 255) / 256;

  // CSR build (atomic-free, full-chip); cast rides along in extra blocks
  k_b1cnt_cast<<<P_SORT + 256, 256, 0, stream>>>(dst, bcnt, W_gat, W_gcn, Wt, E, epb, nbkt);
  k_scan1  <<<nbs, 256, 0, stream>>>(bcnt, incl, blockSums, M);
  k_scan2  <<<1,   256, 0, stream>>>(blockSums, blockOffs, nbs);
  k_b1place<<<P_SORT, 256, 0, stream>>>(src, dst, emask, incl, bcnt, blockOffs,
                                        tpw, E, epb, nbkt);
  k_b2     <<<nbkt, 256, 0, stream>>>(tpw, blockOffs, col_sw, rowp, dinv, N, E, nbkt);

  // xp = x @ W_gat -> int8 rows + attr4 {src-dot, dinv, scale} + sdst
  k_gemm1<<<gb, 128, 0, stream>>>(x, Wt, zq, a_src, a_dst, dinv, attr4, sdst, N);

  // GAT aggregation (single fused sweep), produces h0 bf16 + g0 int8 + scd0
  k_agg0<<<nwb, 256, 0, stream>>>(zq, rowp, col_sw, attr4, sdst,
                                  b_gat, h0, g0q, scd0, N);

  // fused GCN layers: h' = relu((A h) W + b), coeff streams precomputed per layer
  k_ecoef<<<neb, 256, 0, stream>>>(col_sw, scd0, col_eq, E);
  k_fagg<1><<<nfb, 256, 0, stream>>>(g0q, scd0, rowp, col_eq, dinv,
                                     Wt + (size_t)1*16384, b_gcn + 0,
                                     h1, g1q, scd1,
                                     nullptr, nullptr, nullptr, nullptr, N);
  k_ecoef<<<neb, 256, 0, stream>>>(col_sw, scd1, col_eq, E);
  k_fagg<1><<<nfb, 256, 0, stream>>>(g1q, scd1, rowp, col_eq, dinv,
                                     Wt + (size_t)2*16384, b_gcn + 128,
                                     h2, g2q, scd2,
                                     nullptr, nullptr, nullptr, nullptr, N);
  k_ecoef<<<neb, 256, 0, stream>>>(col_sw, scd2, col_eq, E);
  // last layer + fused JK max over {h0, h1, h2, h3} -> fp32 d_out
  k_fagg<2><<<nfb, 256, 0, stream>>>(g2q, scd2, rowp, col_eq, dinv,
                                     Wt + (size_t)3*16384, b_gcn + 256,
                                     nullptr, nullptr, nullptr,
                                     h0, h1, h2, (float*)d_out, N);
}

// Round 8
// 316.384 us; speedup vs baseline: 1.2415x; 1.0905x over previous
//
#include <hip/hip_runtime.h>

#define HIDDEN 128
#define NEG_SLOPE 0.2f
#define P_SORT 256          // blocks for phase-1 bucket sort
#define LCOL_CAP 512        // per-block edge-coeff LDS cache (16 nodes, deg~16 -> ~256)

typedef unsigned short ushort_t;
typedef __attribute__((ext_vector_type(8))) short short8;
typedef __attribute__((ext_vector_type(4))) float floatx4;

static inline size_t align_up(size_t x, size_t a){ return (x + a - 1) & ~(a - 1); }

__device__ __forceinline__ ushort_t f2b(float f){
  unsigned u = __float_as_uint(f);
  unsigned r = (u + 0x7FFFu + ((u >> 16) & 1u)) >> 16;
  return (ushort_t)r;
}

__device__ __forceinline__ float b2f(ushort_t u){
  return __uint_as_float(((unsigned)u) << 16);
}

// int8 row-quantized feature FMA: 8 sbytes in a uint2, coeff a already includes row scale
__device__ __forceinline__ void fma8q(float* acc, uint2 v, float a){
  int x = (int)v.x, y = (int)v.y;
  acc[0] += a * (float)((x << 24) >> 24);
  acc[1] += a * (float)((x << 16) >> 24);
  acc[2] += a * (float)((x <<  8) >> 24);
  acc[3] += a * (float)( x        >> 24);
  acc[4] += a * (float)((y << 24) >> 24);
  acc[5] += a * (float)((y << 16) >> 24);
  acc[6] += a * (float)((y <<  8) >> 24);
  acc[7] += a * (float)( y        >> 24);
}

__device__ __forceinline__ uint2 packq8(const float* f, float qi){
  unsigned a = 0, b = 0;
  int q;
  q = (int)rintf(f[0]*qi); a |= ((unsigned)q & 255u);
  q = (int)rintf(f[1]*qi); a |= ((unsigned)q & 255u) << 8;
  q = (int)rintf(f[2]*qi); a |= ((unsigned)q & 255u) << 16;
  q = (int)rintf(f[3]*qi); a |= ((unsigned)q & 255u) << 24;
  q = (int)rintf(f[4]*qi); b |= ((unsigned)q & 255u);
  q = (int)rintf(f[5]*qi); b |= ((unsigned)q & 255u) << 8;
  q = (int)rintf(f[6]*qi); b |= ((unsigned)q & 255u) << 16;
  q = (int)rintf(f[7]*qi); b |= ((unsigned)q & 255u) << 24;
  uint2 r; r.x = a; r.y = b; return r;
}

__device__ __forceinline__ uint4 pack8(const float* f){
  uint4 u;
  u.x = (unsigned)f2b(f[0]) | ((unsigned)f2b(f[1]) << 16);
  u.y = (unsigned)f2b(f[2]) | ((unsigned)f2b(f[3]) << 16);
  u.z = (unsigned)f2b(f[4]) | ((unsigned)f2b(f[5]) << 16);
  u.w = (unsigned)f2b(f[6]) | ((unsigned)f2b(f[7]) << 16);
  return u;
}

// ============ CSR build: two-pass bucketed counting sort ============
// merged: blocks [0, P_SORT) do the bucket count; blocks [P_SORT, P_SORT+256)
// do the independent weight cast (4 mats fp32 -> transposed bf16).

__global__ __launch_bounds__(256) void k_b1cnt_cast(const int* __restrict__ dst,
                                                    int* __restrict__ bcnt,
                                                    const float* __restrict__ Wg,
                                                    const float* __restrict__ Wc,
                                                    ushort_t* __restrict__ Wt,
                                                    int E, int epb, int nbkt){
  int t = threadIdx.x;
  if (blockIdx.x >= P_SORT){
    int i = (blockIdx.x - P_SORT)*256 + t;     // 4*16384 elements
    int mat = i >> 14, idx = i & 16383;
    int k = idx >> 7, n = idx & 127;
    float v = (mat == 0) ? Wg[idx] : Wc[(mat-1)*16384 + idx];
    Wt[mat*16384 + n*128 + k] = f2b(v);
    return;
  }
  __shared__ unsigned c[256];
  c[t] = 0;
  __syncthreads();
  int e0 = blockIdx.x * epb;
  int e1 = min(E, e0 + epb);
  for (int e = e0 + t; e < e1; e += 256) atomicAdd(&c[dst[e] >> 8], 1u);
  __syncthreads();
  if (t < nbkt) bcnt[t * P_SORT + blockIdx.x] = (int)c[t];
}

__global__ void k_scan1(const int* __restrict__ in, int* __restrict__ incl,
                        int* __restrict__ blockSums, int M){
  __shared__ int sd[256];
  int t = threadIdx.x;
  int i = blockIdx.x*256 + t;
  int v = (i < M) ? in[i] : 0;
  sd[t] = v; __syncthreads();
  for (int off = 1; off < 256; off <<= 1){
    int add = (t >= off) ? sd[t-off] : 0;
    __syncthreads();
    sd[t] += add;
    __syncthreads();
  }
  if (i < M) incl[i] = sd[t];
  if (t == 255) blockSums[blockIdx.x] = sd[255];
}

// phase-1 scatter; bucket offsets (exclusive scan of blockSums, nbkt<=256 elems)
// recomputed inline in LDS (replaces the old k_scan2 kernel).
__global__ __launch_bounds__(256) void k_b1place(const int* __restrict__ src,
                                                 const int* __restrict__ dst,
                                                 const float* __restrict__ w,
                                                 const int* __restrict__ incl,
                                                 const int* __restrict__ bcnt,
                                                 const int* __restrict__ blockSums,
                                                 int2* __restrict__ tpw,
                                                 int E, int epb, int nbkt){
  __shared__ int base_[256];
  __shared__ unsigned c[256];
  __shared__ int sOf[256];
  int t = threadIdx.x;
  c[t] = 0;
  int bs = (t < nbkt) ? blockSums[t] : 0;
  sOf[t] = bs;
  __syncthreads();
  for (int off = 1; off < 256; off <<= 1){
    int add = (t >= off) ? sOf[t-off] : 0;
    __syncthreads();
    sOf[t] += add;
    __syncthreads();
  }
  if (t < nbkt){
    int idx = t * P_SORT + blockIdx.x;
    base_[t] = incl[idx] - bcnt[idx] + (sOf[t] - bs);   // + exclusive bucket offset
  }
  __syncthreads();
  int e0 = blockIdx.x * epb;
  int e1 = min(E, e0 + epb);
  for (int e = e0 + t; e < e1; e += 256){
    int d = dst[e];
    int b = d >> 8;
    unsigned r = atomicAdd(&c[b], 1u);
    int pos = base_[b] + (int)r;
    tpw[pos] = make_int2((int)((unsigned)src[e] | ((unsigned)(d & 255) << 16)),
                         __float_as_int(w[e]));
  }
}

// phase-2 fine sort: counting sort on key (row, src>>12); bucket range from
// inline scan of blockSums (e0 = sOf[b-1], e1 = sOf[b]).
__global__ __launch_bounds__(256) void k_b2(const int2* __restrict__ tpw,
                                            const int* __restrict__ blockSums,
                                            int2* __restrict__ col_sw,
                                            int* __restrict__ rowp,
                                            float* __restrict__ dinv,
                                            int N, int E, int nbkt){
  __shared__ int cnt[4096];      // 256 rows x 16 src-slices
  __shared__ int tsum[256];
  __shared__ float wsum[256];
  __shared__ int sOf[256];
  int b = blockIdx.x, t = threadIdx.x;
  #pragma unroll
  for (int i = 0; i < 16; i++) cnt[t*16 + i] = 0;
  wsum[t] = 0.f;
  sOf[t] = (t < nbkt) ? blockSums[t] : 0;
  __syncthreads();
  for (int off = 1; off < 256; off <<= 1){
    int add = (t >= off) ? sOf[t-off] : 0;
    __syncthreads();
    sOf[t] += add;
    __syncthreads();
  }
  int e1 = sOf[b];
  int e0 = (b > 0) ? sOf[b-1] : 0;
  for (int e = e0 + t; e < e1; e += 256){
    int2 pw = tpw[e];
    unsigned dl = ((unsigned)pw.x >> 16) & 255u;
    unsigned s  = ((unsigned)pw.x & 0xFFFFu) >> 12;     // src slice 0..15
    atomicAdd(&cnt[(dl << 4) | s], 1);
  }
  __syncthreads();
  int loc[16]; int run = 0;
  #pragma unroll
  for (int i = 0; i < 16; i++){ loc[i] = run; run += cnt[t*16 + i]; }
  tsum[t] = run;
  __syncthreads();
  for (int off = 1; off < 256; off <<= 1){
    int add = (t >= off) ? tsum[t-off] : 0;
    __syncthreads();
    tsum[t] += add;
    __syncthreads();
  }
  int base = tsum[t] - run;                              // exclusive over rows
  #pragma unroll
  for (int i = 0; i < 16; i++) cnt[t*16 + i] = base + loc[i];
  int node = b*256 + t;
  if (node < N) rowp[node] = e0 + base;
  if (b == 0 && t == 0) rowp[N] = E;
  __syncthreads();
  for (int e = e0 + t; e < e1; e += 256){
    int2 pw = tpw[e];
    unsigned dl = ((unsigned)pw.x >> 16) & 255u;
    unsigned srcv = (unsigned)pw.x & 0xFFFFu;
    unsigned s = srcv >> 12;
    int pos = e0 + atomicAdd(&cnt[(dl << 4) | s], 1);    // old value == slot
    col_sw[pos] = make_int2((int)srcv, pw.y);
    atomicAdd(&wsum[dl], __int_as_float(pw.y));
  }
  __syncthreads();
  if (node < N) dinv[node] = rsqrtf(wsum[t] + 1.0f);     // +1 = self-loop weight
}

// ------- MFMA GEMM (GAT layer): xp = x @ W_gat; outputs int8-quantized xp rows
// (zq), packed per-row table attr4 = {a_src dot, dinv, int8 scale, 0}, and sdst. -------
__global__ __launch_bounds__(128) void k_gemm1(const float* __restrict__ Ain,
                                               const ushort_t* __restrict__ Wt,
                                               unsigned* __restrict__ zq,   // N*32B (uint)
                                               const float* __restrict__ a_src,
                                               const float* __restrict__ a_dst,
                                               const float* __restrict__ dinv,
                                               float4* __restrict__ attr4,
                                               float* __restrict__ sdst, int M){
  __shared__ uint4 zq8v[64][8];                 // 64 rows x 128B int8 staging
  char (*zq8)[128] = (char(*)[128])zq8v;
  int wave = threadIdx.x >> 6, l = threadIdx.x & 63;
  int q = l >> 4, lm = l & 15;
  int rowBase = blockIdx.x*64 + wave*32;
  floatx4 acc[2][8];
  #pragma unroll
  for (int mt = 0; mt < 2; mt++)
    #pragma unroll
    for (int nt = 0; nt < 8; nt++) acc[mt][nt] = (floatx4){0.f,0.f,0.f,0.f};

  #pragma unroll
  for (int kc = 0; kc < 4; kc++){
    int k0 = kc*32 + q*8;
    short8 a[2];
    #pragma unroll
    for (int mt = 0; mt < 2; mt++){
      long r = rowBase + mt*16 + lm;
      if (r < M){
        const float* ap = Ain + r*128 + k0;
        float4 u = *(const float4*)ap;
        float4 v = *(const float4*)(ap + 4);
        short8 tv;
        tv[0]=(short)f2b(u.x); tv[1]=(short)f2b(u.y); tv[2]=(short)f2b(u.z); tv[3]=(short)f2b(u.w);
        tv[4]=(short)f2b(v.x); tv[5]=(short)f2b(v.y); tv[6]=(short)f2b(v.z); tv[7]=(short)f2b(v.w);
        a[mt] = tv;
      } else a[mt] = (short8){0,0,0,0,0,0,0,0};
    }
    #pragma unroll
    for (int nt = 0; nt < 8; nt++){
      short8 b = *(const short8*)(Wt + (nt*16 + lm)*128 + k0);
      acc[0][nt] = __builtin_amdgcn_mfma_f32_16x16x32_bf16(a[0], b, acc[0][nt], 0, 0, 0);
      acc[1][nt] = __builtin_amdgcn_mfma_f32_16x16x32_bf16(a[1], b, acc[1][nt], 0, 0, 0);
    }
  }
  // ---- int8 row quantization (C layout: row = rowBase+mt*16+q*4+r, col = nt*16+lm) ----
  float rms[2][4];
  #pragma unroll
  for (int mt = 0; mt < 2; mt++){
    #pragma unroll
    for (int r = 0; r < 4; r++){
      float rm = 0.f;
      #pragma unroll
      for (int nt = 0; nt < 8; nt++) rm = fmaxf(rm, fabsf(acc[mt][nt][r]));
      #pragma unroll
      for (int off = 1; off <= 8; off <<= 1) rm = fmaxf(rm, __shfl_xor(rm, off, 64));
      float qi = (rm > 0.f) ? 127.f/rm : 0.f;
      int lrow = wave*32 + mt*16 + q*4 + r;
      #pragma unroll
      for (int nt = 0; nt < 8; nt++)
        zq8[lrow][nt*16 + lm] = (char)(int)rintf(acc[mt][nt][r]*qi);
      rms[mt][r] = rm * (1.f/127.f);
    }
  }
  // ---- fused attention row dots ----
  float as8[8], ad8[8];
  #pragma unroll
  for (int nt = 0; nt < 8; nt++){ as8[nt] = a_src[nt*16 + lm]; ad8[nt] = a_dst[nt*16 + lm]; }
  #pragma unroll
  for (int mt = 0; mt < 2; mt++){
    #pragma unroll
    for (int r = 0; r < 4; r++){
      float ps = 0.f, pd = 0.f;
      #pragma unroll
      for (int nt = 0; nt < 8; nt++){
        ps += acc[mt][nt][r] * as8[nt];
        pd += acc[mt][nt][r] * ad8[nt];
      }
      #pragma unroll
      for (int off = 1; off <= 8; off <<= 1){
        ps += __shfl_xor(ps, off, 64);
        pd += __shfl_xor(pd, off, 64);
      }
      long row = rowBase + mt*16 + q*4 + r;
      if (lm == 0 && row < M){
        attr4[row] = make_float4(ps, dinv[row], rms[mt][r], 0.f);
        sdst[row] = pd;
      }
    }
  }
  __syncthreads();
  // ---- coalesced dump of int8 rows ----
  {
    int t = threadIdx.x;
    int lrow = t >> 1, half = t & 1;
    long row = (long)blockIdx.x*64 + lrow;
    if (row < M){
      uint4* dq = (uint4*)zq + row*8 + half*4;
      #pragma unroll
      for (int k = 0; k < 4; k++) dq[k] = zq8v[lrow][half*4 + k];
    }
  }
}

// ======= GAT aggregation, single fused sweep: wave per node, 16 lanes/edge =======
// Per edge slot: col -> {attr4 broadcast (L2), int8 feature (HBM)} in parallel.
__global__ __launch_bounds__(256) void k_agg0(const unsigned* __restrict__ zq,
                                              const int* __restrict__ rowp,
                                              const int2* __restrict__ col_sw,
                                              const float4* __restrict__ attr4,
                                              const float* __restrict__ sdst_,
                                              const float* __restrict__ bias,
                                              ushort_t* __restrict__ out,
                                              unsigned* __restrict__ g0,
                                              float* __restrict__ scd0, int N){
  int n = blockIdx.x*4 + (threadIdx.x >> 6);
  if (n >= N) return;
  int l = threadIdx.x & 63;
  int sub = l >> 4, q = l & 15;
  int rs = rowp[n], re = rowp[n+1];
  float4 an = attr4[n];
  float sdd = sdst_[n];
  float es = an.x + sdd;
  es = (es >= 0.f) ? es : NEG_SLOPE*es;
  float pself = __expf(es);

  const uint2* f8 = (const uint2*)zq;
  float acc[8] = {0.f,0.f,0.f,0.f,0.f,0.f,0.f,0.f};
  float ps = 0.f;
  int last = (re > rs) ? re - 1 : 0;
  for (int base = rs; base < re; base += 24){
    int2 p[6];
    #pragma unroll
    for (int j = 0; j < 6; j++){
      int e = base + sub + 4*j;
      p[j] = col_sw[min(e, last)];
    }
    float4 at[6];
    #pragma unroll
    for (int j = 0; j < 6; j++) at[j] = attr4[p[j].x];   // 16-lane broadcast, L2
    uint2 v[6];
    #pragma unroll
    for (int j = 0; j < 6; j++) v[j] = f8[(size_t)p[j].x*16 + q];
    #pragma unroll
    for (int j = 0; j < 6; j++){
      int e = base + sub + 4*j;
      float ee = at[j].x + sdd;
      ee = (ee >= 0.f) ? ee : NEG_SLOPE*ee;
      float pe = (e < re) ? __expf(ee) : 0.f;
      ps += pe;
      fma8q(acc, v[j], pe * at[j].z);
    }
  }
  // softmax denom: each slot's 16 lanes hold identical slot-sum; combine 4 slots
  ps += __shfl_xor(ps, 16, 64);
  ps += __shfl_xor(ps, 32, 64);
  float inv = 1.f / (ps + pself);
  #pragma unroll
  for (int j = 0; j < 8; j++){
    acc[j] += __shfl_xor(acc[j], 16, 64);
    acc[j] += __shfl_xor(acc[j], 32, 64);
  }
  if (sub == 0){
    #pragma unroll
    for (int j = 0; j < 8; j++) acc[j] *= inv;
    fma8q(acc, f8[(size_t)n*16 + q], pself * inv * an.z);
    float4 b0 = ((const float4*)bias)[q*2];
    float4 b1 = ((const float4*)bias)[q*2 + 1];
    acc[0]+=b0.x; acc[1]+=b0.y; acc[2]+=b0.z; acc[3]+=b0.w;
    acc[4]+=b1.x; acc[5]+=b1.y; acc[6]+=b1.z; acc[7]+=b1.w;
    ((uint4*)out)[(size_t)n*16 + q] = pack8(acc);        // bf16 h0 for JK
    float rm = 0.f;
    #pragma unroll
    for (int j = 0; j < 8; j++) rm = fmaxf(rm, fabsf(acc[j]));
    #pragma unroll
    for (int off = 1; off <= 8; off <<= 1) rm = fmaxf(rm, __shfl_xor(rm, off, 64));
    float qi = (rm > 0.f) ? 127.f/rm : 0.f;
    ((uint2*)g0)[(size_t)n*16 + q] = packq8(acc, qi);
    if (l == 0) scd0[n] = rm * (1.f/127.f) * an.y;       // sc0 * dinv[n]
  }
}

// ======= fused GCN layer, int8 gather: h' = relu((A h) W + b) =======
// Block pre-pass caches this block's edge coeffs {src, w*scd_prev[src]} in LDS
// (edge-parallel scd gather; replaces the separate k_ecoef kernel + col_eq
// round-trip). Phase 1 = round-6 proven loop. Phase 2 = inline MFMA x W.
// MODE 1: write bf16 h' + int8 g' + scd'. MODE 2: last layer + JK max -> fp32 out.
template<int MODE>
__global__ __launch_bounds__(256) void k_fagg(const unsigned* __restrict__ gin,
                                              const float* __restrict__ scd_prev,
                                              const int* __restrict__ rowp,
                                              const int2* __restrict__ col_sw,
                                              const float* __restrict__ dinv,
                                              const ushort_t* __restrict__ Wl,
                                              const float* __restrict__ bias,
                                              ushort_t* __restrict__ out,
                                              unsigned* __restrict__ gout,
                                              float* __restrict__ scd_out,
                                              const ushort_t* __restrict__ j0,
                                              const ushort_t* __restrict__ j1,
                                              const ushort_t* __restrict__ j2,
                                              float* __restrict__ yout, int N){
  __shared__ ushort_t At[16][136];             // +8 pad: break LDS bank aliasing
  __shared__ uint4 q8v[16][8];                 // int8 output staging (16 x 128B)
  __shared__ unsigned rmaxs[16];
  __shared__ int2 lcol[LCOL_CAP];              // block-local edge coeff cache
  char (*q8s)[128] = (char(*)[128])q8v;
  int wave = threadIdx.x >> 6, l = threadIdx.x & 63;
  int sub = l >> 4, q = l & 15;
  const uint2* f8 = (const uint2*)gin;
  int tile = blockIdx.x * 16;

  // ---- block pre-pass: edge coeffs into LDS (edge-parallel, scd gather L2-hot) ----
  int E0 = rowp[tile];
  int E1 = rowp[min(tile + 16, N)];
  int ecnt = E1 - E0;
  bool fast = (ecnt <= LCOL_CAP);
  if (fast){
    for (int i = threadIdx.x; i < ecnt; i += 256){
      int2 sw = col_sw[E0 + i];
      lcol[i] = make_int2(sw.x, __float_as_int(__int_as_float(sw.y) * scd_prev[sw.x]));
    }
  }
  if (threadIdx.x < 16) rmaxs[threadIdx.x] = 0u;
  __syncthreads();

  // ---- phase 1: aggregate 4 nodes per wave (round-6 proven loop) ----
  for (int i = 0; i < 4; i++){
    int row = wave*4 + i;
    int n = tile + row;
    int rs = 0, re = 0; float dn = 0.f, sprev = 0.f;
    if (n < N){ rs = rowp[n]; re = rowp[n+1]; dn = dinv[n]; sprev = scd_prev[n]; }
    int last = (re > rs) ? re - 1 : 0;
    float acc[8] = {0.f,0.f,0.f,0.f,0.f,0.f,0.f,0.f};
    if (fast){
      for (int base = rs; base < re; base += 24){
        int2 p[6];
        #pragma unroll
        for (int j = 0; j < 6; j++){
          int e = base + sub + 4*j;
          p[j] = lcol[min(e, last) - E0];
        }
        uint2 v[6];
        #pragma unroll
        for (int j = 0; j < 6; j++) v[j] = f8[(size_t)p[j].x*16 + q];
        #pragma unroll
        for (int j = 0; j < 6; j++){
          int e = base + sub + 4*j;
          fma8q(acc, v[j], (e < re) ? __int_as_float(p[j].y) : 0.f);
        }
      }
    } else {
      // freak-degree fallback (block has > LCOL_CAP edges): inline coeff
      for (int base = rs; base < re; base += 24){
        int2 p[6];
        #pragma unroll
        for (int j = 0; j < 6; j++){
          int e = base + sub + 4*j;
          int2 sw = col_sw[min(e, last)];
          p[j] = make_int2(sw.x, __float_as_int(__int_as_float(sw.y) * scd_prev[sw.x]));
        }
        uint2 v[6];
        #pragma unroll
        for (int j = 0; j < 6; j++) v[j] = f8[(size_t)p[j].x*16 + q];
        #pragma unroll
        for (int j = 0; j < 6; j++){
          int e = base + sub + 4*j;
          fma8q(acc, v[j], (e < re) ? __int_as_float(p[j].y) : 0.f);
        }
      }
    }
    #pragma unroll
    for (int j = 0; j < 8; j++){
      acc[j] += __shfl_xor(acc[j], 16, 64);
      acc[j] += __shfl_xor(acc[j], 32, 64);
    }
    if (sub == 0){
      if (n < N) fma8q(acc, f8[(size_t)n*16 + q], sprev);   // self-loop term
      #pragma unroll
      for (int j = 0; j < 8; j++) acc[j] *= dn;             // hoisted dinv[n]
      *(uint4*)&At[row][q*8] = pack8(acc);                  // zeros for n >= N
    }
  }
  __syncthreads();

  // ---- phase 2: [16x128] @ [128x128] ; wave covers 32 output cols ----
  floatx4 co[2];
  co[0] = (floatx4){0.f,0.f,0.f,0.f};
  co[1] = (floatx4){0.f,0.f,0.f,0.f};
  #pragma unroll
  for (int kc = 0; kc < 4; kc++){
    int k0 = kc*32 + sub*8;
    short8 a = *(const short8*)&At[q][k0];
    #pragma unroll
    for (int ntl = 0; ntl < 2; ntl++){
      int nt = wave*2 + ntl;
      short8 b = *(const short8*)(Wl + (size_t)(nt*16 + q)*128 + k0);
      co[ntl] = __builtin_amdgcn_mfma_f32_16x16x32_bf16(a, b, co[ntl], 0, 0, 0);
    }
  }
  // C layout: col = lane&15 (=q), row = sub*4 + r
  float vv[4][2];
  #pragma unroll
  for (int r = 0; r < 4; r++){
    int row = sub*4 + r;
    int node = tile + row;
    float lmax = 0.f;
    #pragma unroll
    for (int ntl = 0; ntl < 2; ntl++){
      int colg = wave*32 + ntl*16 + q;
      float v = co[ntl][r] + bias[colg];
      v = fmaxf(v, 0.f);                       // all GCN layers ReLU'd
      vv[r][ntl] = v;
      lmax = fmaxf(lmax, v);
      if (node < N){
        size_t idx = (size_t)node*128 + colg;
        if (MODE == 1){
          out[idx] = f2b(v);                   // bf16 h' for JK
        } else {
          float m = fmaxf(fmaxf(b2f(j0[idx]), b2f(j1[idx])),
                          fmaxf(b2f(j2[idx]), v));
          yout[idx] = m;
        }
      }
    }
    if (MODE == 1) atomicMax(&rmaxs[row], __float_as_uint(lmax));  // v>=0: bits ordered
  }
  if (MODE == 1){
    __syncthreads();
    #pragma unroll
    for (int r = 0; r < 4; r++){
      int row = sub*4 + r;
      float rm = __uint_as_float(rmaxs[row]);
      float qi = (rm > 0.f) ? 127.f/rm : 0.f;
      #pragma unroll
      for (int ntl = 0; ntl < 2; ntl++){
        int colg = wave*32 + ntl*16 + q;
        q8s[row][colg] = (char)(int)rintf(vv[r][ntl]*qi);
      }
    }
    if (threadIdx.x < 16){
      int node = tile + threadIdx.x;
      if (node < N){
        float rm = __uint_as_float(rmaxs[threadIdx.x]);
        scd_out[node] = rm * (1.f/127.f) * dinv[node];
      }
    }
    __syncthreads();
    if (threadIdx.x < 128){
      int row = threadIdx.x >> 3, c = threadIdx.x & 7;
      int node = tile + row;
      if (node < N) ((uint4*)gout)[(size_t)node*8 + c] = q8v[row][c];
    }
  }
}

extern "C" void kernel_launch(void* const* d_in, const int* in_sizes, int n_in,
                              void* d_out, int out_size, void* d_ws, size_t ws_size,
                              hipStream_t stream){
  const float* x      = (const float*)d_in[0];
  const int*   eidx   = (const int*)d_in[1];
  const float* emask  = (const float*)d_in[2];
  const float* W_gat  = (const float*)d_in[3];
  const float* a_src  = (const float*)d_in[4];
  const float* a_dst  = (const float*)d_in[5];
  const float* b_gat  = (const float*)d_in[6];
  const float* W_gcn  = (const float*)d_in[7];
  const float* b_gcn  = (const float*)d_in[8];
  int N = in_sizes[0] / HIDDEN;
  int E = in_sizes[1] / 2;
  const int* src = eidx;
  const int* dst = eidx + E;

  char* p = (char*)d_ws;
  auto carve = [&](size_t bytes)->char*{ char* q = p; p += align_up(bytes, 512); return q; };
  ushort_t* h0   = (ushort_t*)carve((size_t)N*HIDDEN*2);
  ushort_t* h1   = (ushort_t*)carve((size_t)N*HIDDEN*2);
  ushort_t* h2   = (ushort_t*)carve((size_t)N*HIDDEN*2);
  ushort_t* Wt   = (ushort_t*)carve((size_t)4*HIDDEN*HIDDEN*2);
  unsigned* zq   = (unsigned*)carve((size_t)N*HIDDEN);      // int8 matrices (128B rows)
  unsigned* g0q  = (unsigned*)carve((size_t)N*HIDDEN);
  unsigned* g1q  = (unsigned*)carve((size_t)N*HIDDEN);
  unsigned* g2q  = (unsigned*)carve((size_t)N*HIDDEN);
  float* scd0    = (float*)carve((size_t)N*4);
  float* scd1    = (float*)carve((size_t)N*4);
  float* scd2    = (float*)carve((size_t)N*4);
  float4* attr4  = (float4*)carve((size_t)N*16);
  float* sdst    = (float*)carve((size_t)N*4);
  float* dinv    = (float*)carve((size_t)N*4);
  int*   rowp    = (int*)  carve((size_t)(N+1)*4);
  int2*  col_sw  = (int2*) carve((size_t)E*8);
  int2*  tpw     = (int2*) carve((size_t)E*8);
  int nbkt = (N + 255) >> 8;                       // 196
  int M    = nbkt * P_SORT;                        // 50176
  int*   bcnt  = (int*)carve((size_t)M*4);
  int*   incl  = (int*)carve((size_t)M*4);
  int nbs = (M + 255) / 256;                       // == nbkt
  int*   blockSums = (int*)carve((size_t)nbs*4);
  (void)ws_size; (void)n_in; (void)out_size;

  int epb = (E + P_SORT - 1) / P_SORT;
  int gb  = (N + 63) / 64;
  int nwb = (N + 3) / 4;
  int nfb = (N + 15) / 16;

  // CSR build (atomic-free, full-chip); cast rides along in extra blocks
  k_b1cnt_cast<<<P_SORT + 256, 256, 0, stream>>>(dst, bcnt, W_gat, W_gcn, Wt, E, epb, nbkt);
  k_scan1  <<<nbs, 256, 0, stream>>>(bcnt, incl, blockSums, M);
  k_b1place<<<P_SORT, 256, 0, stream>>>(src, dst, emask, incl, bcnt, blockSums,
                                        tpw, E, epb, nbkt);
  k_b2     <<<nbkt, 256, 0, stream>>>(tpw, blockSums, col_sw, rowp, dinv, N, E, nbkt);

  // xp = x @ W_gat -> int8 rows + attr4 {src-dot, dinv, scale} + sdst
  k_gemm1<<<gb, 128, 0, stream>>>(x, Wt, zq, a_src, a_dst, dinv, attr4, sdst, N);

  // GAT aggregation (single fused sweep), produces h0 bf16 + g0 int8 + scd0
  k_agg0<<<nwb, 256, 0, stream>>>(zq, rowp, col_sw, attr4, sdst,
                                  b_gat, h0, g0q, scd0, N);

  // fused GCN layers: h' = relu((A h) W + b); edge coeffs cached per-block in LDS
  k_fagg<1><<<nfb, 256, 0, stream>>>(g0q, scd0, rowp, col_sw, dinv,
                                     Wt + (size_t)1*16384, b_gcn + 0,
                                     h1, g1q, scd1,
                                     nullptr, nullptr, nullptr, nullptr, N);
  k_fagg<1><<<nfb, 256, 0, stream>>>(g1q, scd1, rowp, col_sw, dinv,
                                     Wt + (size_t)2*16384, b_gcn + 128,
                                     h2, g2q, scd2,
                                     nullptr, nullptr, nullptr, nullptr, N);
  // last layer + fused JK max over {h0, h1, h2, h3} -> fp32 d_out
  k_fagg<2><<<nfb, 256, 0, stream>>>(g2q, scd2, rowp, col_sw, dinv,
                                     Wt + (size_t)3*16384, b_gcn + 256,
                                     nullptr, nullptr, nullptr,
                                     h0, h1, h2, (float*)d_out, N);
}